// Round 4
// baseline (3193.943 us; speedup 1.0000x reference)
//
#include <hip/hip_runtime.h>
#include <hip/hip_bf16.h>

// R4: eliminate ALL per-edge global atomics (k_deg 279us + k_fill ~250us were
// memory-side-RMW bound, 23 G atomic/s). Two-level LDS counting sort by dst
// bucket (dst>>7), then per-bucket LDS-accumulator aggregation (ds_add_f32).
// Fallback to R3 CSR path if ws < 66.02 MB.

#define NN 100000
#define NE 3200000
#define INV_N (1.0f/100000.0f)
#define BN_EPS 1e-5f
#define NBK 782            // buckets of 128 nodes
#define NSB 512            // scatter/hist blocks
#define EPB 6250           // edges per scatter/hist block (NSB*EPB == NE)

static __device__ __forceinline__ float bf2f(unsigned short u) {
    if ((u & 0x7f80u) == 0x7f80u) u = 0;          // inf/NaN -> 0 (scrub)
    union { unsigned int i; float f; } z; z.i = ((unsigned int)u) << 16; return z.f;
}
static __device__ __forceinline__ float scrubf(float v) {
    return (fabsf(v) < 1e30f) ? v : 0.f;
}
static __device__ __forceinline__ unsigned short f2bf(float v) {
    union { float f; unsigned int i; } z; z.f = v;
    unsigned int lsb = (z.i >> 16) & 1u; z.i += 0x7fffu + lsb;
    return (unsigned short)(z.i >> 16);
}
static __device__ __forceinline__ float ld1(const void* p, size_t i, int f) {
    return f ? scrubf(((const float*)p)[i]) : bf2f(((const unsigned short*)p)[i]);
}
static __device__ __forceinline__ float4 ld4(const void* p, size_t g, int f) {
    if (f) { float4 v = ((const float4*)p)[g];
             return make_float4(scrubf(v.x),scrubf(v.y),scrubf(v.z),scrubf(v.w)); }
    ushort4 u = ((const ushort4*)p)[g];
    return make_float4(bf2f(u.x),bf2f(u.y),bf2f(u.z),bf2f(u.w));
}
static __device__ __forceinline__ int getidx(const int* ei, size_t pos, int i64) {
    return i64 ? ei[2*pos] : ei[pos];
}

// ---------------- dtype / index-width detector ----------------
__global__ void k_detect(const unsigned short* __restrict__ x,
                         const int* __restrict__ ei, int* __restrict__ flag) {
    __shared__ int cnt[256];
    int tid = threadIdx.x, c = 0;
    for (int i = tid; i < 1024; i += 256) {
        unsigned short u = x[i];
        int ex = (u >> 7) & 0xff;
        if ((u & 0x7fffu) != 0 && (ex >= 0xB0 || ex <= 0x40)) c++;
    }
    cnt[tid] = c; __syncthreads();
    if (tid == 0) { int t = 0; for (int i = 0; i < 256; ++i) t += cnt[i];
                    flag[0] = (t > 64) ? 1 : 0; }          // 1 = floats are f32
    if (tid == 1) { int nz = 0; for (int i = 1; i < 64; i += 2) nz |= ei[i];
                    flag[1] = (nz == 0) ? 1 : 0; }         // 1 = edge_index is int64
}

__global__ void k_init(float* __restrict__ dis, float* __restrict__ sums,
                       int* __restrict__ cnt) {
    int i = blockIdx.x * 256 + threadIdx.x;
    if (i < NN)  dis[i] = 1.0f;
    if (i < 384) sums[i] = 0.0f;
    if (cnt && i < NN) cnt[i] = 0;
}

// ================= NEW PATH: LDS counting sort =================

__global__ __launch_bounds__(256) void k_hist(const int* __restrict__ flag,
                                              const int* __restrict__ ei,
                                              int* __restrict__ histmat) {
    __shared__ int hh[NBK];
    const int i64 = flag[1];
    const int blk = blockIdx.x, tid = threadIdx.x;
    for (int b = tid; b < NBK; b += 256) hh[b] = 0;
    __syncthreads();
    const size_t e0 = (size_t)blk * EPB;
    for (int e = tid; e < EPB; e += 256) {
        unsigned d = (unsigned)getidx(ei, NE + e0 + e, i64);
        if (d < NN) atomicAdd(&hh[d >> 7], 1);
    }
    __syncthreads();
    for (int b = tid; b < NBK; b += 256) histmat[blk*NBK + b] = hh[b];
}

// per-bucket column scan across the NSB blocks (exclusive), total -> btot
__global__ __launch_bounds__(256) void k_scanA(int* __restrict__ histmat,
                                               int* __restrict__ btot) {
    __shared__ int sd[256];
    const int b = blockIdx.x, t = threadIdx.x;
    int v0 = histmat[(2*t)*NBK + b];
    int v1 = histmat[(2*t+1)*NBK + b];
    int ts = v0 + v1;
    sd[t] = ts; __syncthreads();
    #pragma unroll
    for (int ofs = 1; ofs < 256; ofs <<= 1) {
        int a = (t >= ofs) ? sd[t-ofs] : 0;
        __syncthreads();
        sd[t] += a;
        __syncthreads();
    }
    int excl = sd[t] - ts;
    histmat[(2*t)*NBK + b]   = excl;
    histmat[(2*t+1)*NBK + b] = excl + v0;
    if (t == 255) btot[b] = sd[255];
}

__global__ void k_scanB(const int* __restrict__ btot, int* __restrict__ bstart) {
    __shared__ int sd[1024];
    int t = threadIdx.x;                 // 1024 threads
    int v = (t < NBK) ? btot[t] : 0;
    sd[t] = v; __syncthreads();
    #pragma unroll
    for (int ofs = 1; ofs < 1024; ofs <<= 1) {
        int a = (t >= ofs) ? sd[t-ofs] : 0;
        __syncthreads();
        sd[t] += a;
        __syncthreads();
    }
    if (t <= NBK) bstart[t] = sd[t] - v;   // exclusive; bstart[NBK] = total
}

// scatter edges into bucket-grouped arrays; only LDS atomics
__global__ __launch_bounds__(256) void k_scatter(
    const int* __restrict__ flag, const int* __restrict__ ei,
    const void* __restrict__ ew, const int* __restrict__ histmat,
    const int* __restrict__ bstart, unsigned* __restrict__ packed,
    float* __restrict__ wts) {
    __shared__ int cursor[NBK];
    const int f = flag[0], i64 = flag[1];
    const int blk = blockIdx.x, tid = threadIdx.x;
    for (int b = tid; b < NBK; b += 256)
        cursor[b] = histmat[blk*NBK + b] + bstart[b];
    __syncthreads();
    const size_t e0 = (size_t)blk * EPB;
    for (int e = tid; e < EPB; e += 256) {
        unsigned d = (unsigned)getidx(ei, NE + e0 + e, i64);
        if (d >= NN) continue;
        unsigned s = (unsigned)getidx(ei, e0 + e, i64);
        float w = ld1(ew, e0 + e, f);
        if (s >= NN) { s = 0; w = 0.f; }
        int pos = atomicAdd(&cursor[d >> 7], 1);
        packed[pos] = ((d & 127u) << 17) | s;
        wts[pos] = w;
    }
}

// per-bucket degree -> dis = rsqrt(1 + sum w)
__global__ __launch_bounds__(256) void k_bucketdeg(
    const int* __restrict__ bstart, const unsigned* __restrict__ packed,
    const float* __restrict__ wts, float* __restrict__ dis) {
    __shared__ float degf[128];
    const int b = blockIdx.x, tid = threadIdx.x;
    if (tid < 128) degf[tid] = 1.0f;
    __syncthreads();
    const int r0 = bstart[b], r1 = bstart[b+1];
    for (int j = r0 + tid; j < r1; j += 256)
        atomicAdd(&degf[(packed[j] >> 17) & 127], wts[j]);
    __syncthreads();
    if (tid < 128) {
        int node = b*128 + tid;
        if (node < NN) dis[node] = rsqrtf(fmaxf(degf[tid], 1e-12f));
    }
}

// per-bucket aggregation: LDS 128x64 accumulator, wave-per-edge ds_add_f32
__global__ __launch_bounds__(256) void k_agg(
    const int* __restrict__ flag, const int* __restrict__ bstart,
    const unsigned* __restrict__ packed, const float* __restrict__ wts,
    const float* __restrict__ dis, const void* __restrict__ bias,
    const unsigned short* __restrict__ h, float* __restrict__ agg) {
    __shared__ __align__(16) float acc[128*64];
    __shared__ float disloc[128];
    const int f = flag[0];
    const int b = blockIdx.x, tid = threadIdx.x;
    const int lane = tid & 63, wv = tid >> 6;
    const int node0 = b * 128;
    if (tid < 128) {
        int node = node0 + tid;
        disloc[tid] = (node < NN) ? dis[node] : 0.f;
    }
    __syncthreads();
    const float bl = ld1(bias, lane, f);
    #pragma unroll
    for (int i = tid; i < 128*64; i += 256) {
        int l = i >> 6, node = node0 + l;
        float v = 0.f;
        if (node < NN) {
            float dd = disloc[l];
            v = bl + dd*dd*bf2f(h[(size_t)node*64 + lane]);
        }
        acc[i] = v;
    }
    __syncthreads();
    int j = bstart[b] + wv;
    const int end = bstart[b+1];
    for (; j + 12 < end; j += 16) {          // 4-edge unroll per wave
        unsigned p0 = packed[j],   p1 = packed[j+4];
        unsigned p2 = packed[j+8], p3 = packed[j+12];
        float w0 = wts[j],   w1 = wts[j+4];
        float w2 = wts[j+8], w3 = wts[j+12];
        int s0 = p0 & 0x1ffff, s1 = p1 & 0x1ffff;
        int s2 = p2 & 0x1ffff, s3 = p3 & 0x1ffff;
        int l0 = (p0 >> 17) & 127, l1 = (p1 >> 17) & 127;
        int l2 = (p2 >> 17) & 127, l3 = (p3 >> 17) & 127;
        float c0 = w0 * dis[s0] * disloc[l0];
        float c1 = w1 * dis[s1] * disloc[l1];
        float c2 = w2 * dis[s2] * disloc[l2];
        float c3 = w3 * dis[s3] * disloc[l3];
        float h0 = bf2f(h[(size_t)s0*64 + lane]);
        float h1 = bf2f(h[(size_t)s1*64 + lane]);
        float h2 = bf2f(h[(size_t)s2*64 + lane]);
        float h3 = bf2f(h[(size_t)s3*64 + lane]);
        atomicAdd(&acc[l0*64 + lane], c0*h0);
        atomicAdd(&acc[l1*64 + lane], c1*h1);
        atomicAdd(&acc[l2*64 + lane], c2*h2);
        atomicAdd(&acc[l3*64 + lane], c3*h3);
    }
    for (; j < end; j += 4) {
        unsigned p = packed[j];
        int s = p & 0x1ffff, l = (p >> 17) & 127;
        float c = wts[j] * dis[s] * disloc[l];
        atomicAdd(&acc[l*64 + lane], c * bf2f(h[(size_t)s*64 + lane]));
    }
    __syncthreads();
    #pragma unroll
    for (int i = tid; i < 128*64; i += 256) {
        int node = node0 + (i >> 6);
        if (node < NN) agg[(size_t)node*64 + lane] = acc[i];
    }
}

// ================= FALLBACK (R3) kernels =================

__global__ void k_deg(const int* __restrict__ flag, const int* __restrict__ ei,
                      const void* __restrict__ ew, float* __restrict__ deg,
                      int* __restrict__ cnt) {
    const int f = flag[0], i64 = flag[1];
    int e = blockIdx.x * 256 + threadIdx.x;
    unsigned d = (unsigned)getidx(ei, NE + (size_t)e, i64);
    if (d < NN) {
        unsafeAtomicAdd(&deg[d], ld1(ew, e, f));
        if (cnt) atomicAdd(&cnt[d], 1);
    }
}

__global__ void k_rsqrt(float* __restrict__ dis) {
    int i = blockIdx.x * 256 + threadIdx.x;
    if (i < NN) dis[i] = rsqrtf(fmaxf(dis[i], 1e-12f));
}

__global__ void k_scan1(const int* __restrict__ cnt, int* __restrict__ rowptr,
                        int* __restrict__ blocksum) {
    __shared__ int sd[256];
    int t = threadIdx.x, i = blockIdx.x*256 + t;
    int v = (i < NN) ? cnt[i] : 0;
    sd[t] = v; __syncthreads();
    #pragma unroll
    for (int ofs = 1; ofs < 256; ofs <<= 1) {
        int a = (t >= ofs) ? sd[t-ofs] : 0;
        __syncthreads(); sd[t] += a; __syncthreads();
    }
    if (i < NN) rowptr[i] = sd[t] - v;
    if (t == 255) blocksum[blockIdx.x] = sd[255];
}
__global__ void k_scan2(int* __restrict__ blocksum) {
    __shared__ int sd[512];
    int t = threadIdx.x;
    int v = (t < 391) ? blocksum[t] : 0;
    sd[t] = v; __syncthreads();
    #pragma unroll
    for (int ofs = 1; ofs < 512; ofs <<= 1) {
        int a = (t >= ofs) ? sd[t-ofs] : 0;
        __syncthreads(); sd[t] += a; __syncthreads();
    }
    if (t < 391) blocksum[t] = sd[t] - v;
}
__global__ void k_scan3(int* __restrict__ rowptr, const int* __restrict__ blocksum,
                        int* __restrict__ cursor) {
    int i = blockIdx.x*256 + threadIdx.x;
    if (i < NN) { int r = rowptr[i] + blocksum[blockIdx.x]; rowptr[i] = r; cursor[i] = r; }
}

__global__ void k_fill(const int* __restrict__ flag, const int* __restrict__ ei,
                       const void* __restrict__ ew, const float* __restrict__ dis,
                       int* __restrict__ cursor, int* __restrict__ srcs,
                       float* __restrict__ coefs) {
    const int f = flag[0], i64 = flag[1];
    int e = blockIdx.x * 256 + threadIdx.x;
    unsigned s = (unsigned)getidx(ei, (size_t)e, i64);
    unsigned d = (unsigned)getidx(ei, NE + (size_t)e, i64);
    if (s >= NN || d >= NN) return;
    float coef = dis[s] * ld1(ew, e, f) * dis[d];
    int pos = atomicAdd(&cursor[d], 1);
    srcs[pos] = (int)s;
    coefs[pos] = coef;
}

__global__ __launch_bounds__(256) void k_gather(
    const int* __restrict__ flag, const int* __restrict__ rowptr,
    const int* __restrict__ rowend, const int* __restrict__ srcs,
    const float* __restrict__ coefs, const float* __restrict__ dis,
    const void* __restrict__ bias, const unsigned short* __restrict__ h,
    float* __restrict__ agg) {
    const int f = flag[0];
    int node = blockIdx.x * 4 + (threadIdx.x >> 6);
    int lane = threadIdx.x & 63;
    float d2 = dis[node];
    float acc = ld1(bias, lane, f) + d2*d2*bf2f(h[(size_t)node*64 + lane]);
    int j = rowptr[node], end = rowend[node];
    for (; j + 4 <= end; j += 4) {
        int   s0 = srcs[j],  s1 = srcs[j+1],  s2 = srcs[j+2],  s3 = srcs[j+3];
        float c0 = coefs[j], c1 = coefs[j+1], c2 = coefs[j+2], c3 = coefs[j+3];
        acc = fmaf(c0, bf2f(h[(size_t)s0*64+lane]), acc);
        acc = fmaf(c1, bf2f(h[(size_t)s1*64+lane]), acc);
        acc = fmaf(c2, bf2f(h[(size_t)s2*64+lane]), acc);
        acc = fmaf(c3, bf2f(h[(size_t)s3*64+lane]), acc);
    }
    for (; j < end; ++j)
        acc = fmaf(coefs[j], bf2f(h[(size_t)srcs[j]*64 + lane]), acc);
    agg[(size_t)node*64 + lane] = acc;
}

// ================= shared dense kernels =================

__global__ __launch_bounds__(256) void k_gemm1(
    const int* __restrict__ flag, const void* __restrict__ x,
    const void* __restrict__ W, const void* __restrict__ bias,
    const float* __restrict__ dis,
    unsigned short* __restrict__ h_out, float* __restrict__ agg_out) {
    __shared__ __align__(16) float ws[128*64];
    __shared__ __align__(16) float xs[64*64];
    const int f = flag[0];
    const int tid = threadIdx.x;
    const int rowbase = blockIdx.x * 64;
    #pragma unroll
    for (int it = 0; it < 8; ++it) {
        int g = it*256 + tid;
        float4 v = ld4(W, g, f);
        int b = g*4;
        ws[b]=v.x; ws[b+1]=v.y; ws[b+2]=v.z; ws[b+3]=v.w;
    }
    const int tr = (tid >> 4) << 2;
    const int tc = (tid & 15) << 2;
    const int row = tid & 63;
    const int grow = rowbase + row;
    const bool valid = grow < NN;
    float acc[4][4] = {};
    for (int half = 0; half < 2; ++half) {
        __syncthreads();
        #pragma unroll
        for (int it = 0; it < 4; ++it) {
            int f4 = (tid >> 6) + it*4;
            int kl = f4*4;
            float4 v = make_float4(0,0,0,0);
            if (valid) v = ld4(x, (size_t)grow*32 + half*16 + f4, f);
            xs[(kl+0)*64+row]=v.x; xs[(kl+1)*64+row]=v.y;
            xs[(kl+2)*64+row]=v.z; xs[(kl+3)*64+row]=v.w;
        }
        __syncthreads();
        #pragma unroll 8
        for (int k = 0; k < 64; ++k) {
            const float4 av = *(const float4*)&xs[k*64 + tr];
            const float4 wv = *(const float4*)&ws[(half*64 + k)*64 + tc];
            const float aa[4] = {av.x, av.y, av.z, av.w};
            const float ww[4] = {wv.x, wv.y, wv.z, wv.w};
            #pragma unroll
            for (int i = 0; i < 4; ++i)
                #pragma unroll
                for (int j = 0; j < 4; ++j)
                    acc[i][j] = fmaf(aa[i], ww[j], acc[i][j]);
        }
    }
    float bc[4];
    #pragma unroll
    for (int j = 0; j < 4; ++j) bc[j] = ld1(bias, tc+j, f);
    #pragma unroll
    for (int i = 0; i < 4; ++i) {
        int r = rowbase + tr + i;
        if (r < NN) {
            ushort4 hv = make_ushort4(f2bf(acc[i][0]), f2bf(acc[i][1]),
                                      f2bf(acc[i][2]), f2bf(acc[i][3]));
            *(ushort4*)&h_out[(size_t)r*64 + tc] = hv;
            if (agg_out) {
                float dd = dis[r]; float idg = dd*dd;
                *(float4*)&agg_out[(size_t)r*64 + tc] =
                    make_float4(acc[i][0]*idg+bc[0], acc[i][1]*idg+bc[1],
                                acc[i][2]*idg+bc[2], acc[i][3]*idg+bc[3]);
            }
        }
    }
}

__global__ __launch_bounds__(256) void k_bnstats(const float* __restrict__ src,
                                                 float* __restrict__ sumout, int relu) {
    const int tid = threadIdx.x;
    float s = 0.f, q = 0.f;
    for (int i = blockIdx.x*256 + tid; i < NN*64; i += 512*256) {
        float v = src[i];
        if (relu) v = fmaxf(v, 0.f);
        s += v; q += v*v;
    }
    __shared__ float ls[256], lq[256];
    ls[tid] = s; lq[tid] = q;
    __syncthreads();
    if (tid < 64) {
        s = ls[tid]+ls[tid+64]+ls[tid+128]+ls[tid+192];
        q = lq[tid]+lq[tid+64]+lq[tid+128]+lq[tid+192];
        unsafeAtomicAdd(&sumout[tid], s);
        unsafeAtomicAdd(&sumout[64+tid], q);
    }
}

template<bool RELU, bool AGG>
__global__ __launch_bounds__(256) void k_gemm64(
    const int* __restrict__ flag, const float* __restrict__ in,
    const void* __restrict__ W, const void* __restrict__ bias,
    const void* __restrict__ g, const void* __restrict__ bb,
    const float* __restrict__ insums, const float* __restrict__ dis,
    unsigned short* __restrict__ h_out, float* __restrict__ y_out,
    float* __restrict__ outsums) {
    __shared__ __align__(16) float ws[64*64];
    __shared__ __align__(16) float xs[64*64];
    __shared__ float sc[64], sh[64];
    const int f = flag[0];
    const int tid = threadIdx.x;
    const int rowbase = blockIdx.x * 64;
    if (tid < 64) {
        float mean = insums[tid] * INV_N;
        float var  = fmaxf(insums[64+tid] * INV_N - mean*mean, 0.f);
        float s = ld1(g, tid, f) * rsqrtf(var + BN_EPS);
        sc[tid] = s;
        sh[tid] = ld1(bb, tid, f) - mean*s;
    }
    #pragma unroll
    for (int it = 0; it < 4; ++it) {
        int gi = it*256 + tid;
        float4 v = ld4(W, gi, f);
        int b = gi*4;
        ws[b]=v.x; ws[b+1]=v.y; ws[b+2]=v.z; ws[b+3]=v.w;
    }
    __syncthreads();
    {
        int row = tid & 63;
        int grow = rowbase + row;
        bool valid = grow < NN;
        #pragma unroll
        for (int it = 0; it < 4; ++it) {
            int f4 = (tid >> 6) + it*4;
            int k = f4*4;
            float4 v = make_float4(0,0,0,0);
            if (valid) v = *(const float4*)&in[(size_t)grow*64 + k];
            float a0=v.x, a1=v.y, a2=v.z, a3=v.w;
            if (RELU) { a0=fmaxf(a0,0.f); a1=fmaxf(a1,0.f); a2=fmaxf(a2,0.f); a3=fmaxf(a3,0.f); }
            a0 = a0*sc[k+0]+sh[k+0]; a1 = a1*sc[k+1]+sh[k+1];
            a2 = a2*sc[k+2]+sh[k+2]; a3 = a3*sc[k+3]+sh[k+3];
            xs[(k+0)*64+row]=a0; xs[(k+1)*64+row]=a1;
            xs[(k+2)*64+row]=a2; xs[(k+3)*64+row]=a3;
        }
    }
    __syncthreads();
    const int tr = (tid >> 4) << 2;
    const int tc = (tid & 15) << 2;
    float acc[4][4] = {};
    #pragma unroll 8
    for (int k = 0; k < 64; ++k) {
        const float4 av = *(const float4*)&xs[k*64 + tr];
        const float4 wv = *(const float4*)&ws[k*64 + tc];
        const float aa[4] = {av.x, av.y, av.z, av.w};
        const float ww[4] = {wv.x, wv.y, wv.z, wv.w};
        #pragma unroll
        for (int i = 0; i < 4; ++i)
            #pragma unroll
            for (int j = 0; j < 4; ++j)
                acc[i][j] = fmaf(aa[i], ww[j], acc[i][j]);
    }
    float bc[4];
    #pragma unroll
    for (int j = 0; j < 4; ++j) bc[j] = ld1(bias, tc+j, f);
    if (AGG) {
        #pragma unroll
        for (int i = 0; i < 4; ++i) {
            int r = rowbase + tr + i;
            if (r < NN) {
                ushort4 hv = make_ushort4(f2bf(acc[i][0]), f2bf(acc[i][1]),
                                          f2bf(acc[i][2]), f2bf(acc[i][3]));
                *(ushort4*)&h_out[(size_t)r*64 + tc] = hv;
                if (y_out) {
                    float dd = dis[r]; float idg = dd*dd;
                    *(float4*)&y_out[(size_t)r*64 + tc] =
                        make_float4(acc[i][0]*idg+bc[0], acc[i][1]*idg+bc[1],
                                    acc[i][2]*idg+bc[2], acc[i][3]*idg+bc[3]);
                }
            }
        }
    } else {
        float ps[4] = {0,0,0,0}, pq[4] = {0,0,0,0};
        #pragma unroll
        for (int i = 0; i < 4; ++i) {
            int r = rowbase + tr + i;
            if (r < NN) {
                float y0 = acc[i][0]+bc[0], y1 = acc[i][1]+bc[1];
                float y2 = acc[i][2]+bc[2], y3 = acc[i][3]+bc[3];
                *(float4*)&y_out[(size_t)r*64 + tc] = make_float4(y0,y1,y2,y3);
                ps[0]+=y0; ps[1]+=y1; ps[2]+=y2; ps[3]+=y3;
                pq[0]+=y0*y0; pq[1]+=y1*y1; pq[2]+=y2*y2; pq[3]+=y3*y3;
            }
        }
        __syncthreads();
        int grp = tid >> 4;
        #pragma unroll
        for (int j = 0; j < 4; ++j) { xs[grp*64 + tc+j] = ps[j]; ws[grp*64 + tc+j] = pq[j]; }
        __syncthreads();
        if (tid < 64) {
            float s = 0.f, q = 0.f;
            #pragma unroll
            for (int g2 = 0; g2 < 16; ++g2) { s += xs[g2*64+tid]; q += ws[g2*64+tid]; }
            unsafeAtomicAdd(&outsums[tid], s);
            unsafeAtomicAdd(&outsums[64+tid], q);
        }
    }
}

__global__ __launch_bounds__(256) void k_final(
    const int* __restrict__ flag, const float* __restrict__ y3,
    const void* __restrict__ g, const void* __restrict__ bb,
    const float* __restrict__ sums, const void* __restrict__ w2,
    const void* __restrict__ b2, void* __restrict__ out) {
    __shared__ __align__(16) float tile[64*64];
    __shared__ float wp[64], tv[64];
    const int f = flag[0];
    const int tid = threadIdx.x;
    const int base = blockIdx.x * 64;
    if (tid < 64) {
        float mean = sums[tid] * INV_N;
        float var  = fmaxf(sums[64+tid] * INV_N - mean*mean, 0.f);
        float s = ld1(g, tid, f) * rsqrtf(var + BN_EPS);
        float t = ld1(bb, tid, f) - mean*s;
        float w = ld1(w2, tid, f);
        wp[tid] = s*w; tv[tid] = t*w;
    }
    #pragma unroll
    for (int it = 0; it < 4; ++it) {
        int i4 = it*256 + tid;
        int row = i4 >> 4;
        float4 v = make_float4(0,0,0,0);
        if (base + row < NN) v = *(const float4*)&y3[(size_t)base*64 + i4*4];
        *(float4*)&tile[i4*4] = v;
    }
    __syncthreads();
    if (tid < 64 && base + tid < NN) {
        float a = ld1(b2, 0, f);
        #pragma unroll
        for (int c = 0; c < 64; ++c) a += tv[c];
        #pragma unroll
        for (int cc = 0; cc < 64; ++cc) {
            int c = (cc + tid) & 63;
            a += tile[tid*64 + c] * wp[c];
        }
        if (f) ((float*)out)[base + tid] = a;
        else   ((unsigned short*)out)[base + tid] = f2bf(a);
    }
}

extern "C" void kernel_launch(void* const* d_in, const int* in_sizes, int n_in,
                              void* d_out, int out_size, void* d_ws, size_t ws_size,
                              hipStream_t stream) {
    const unsigned short* x = (const unsigned short*)d_in[0];
    const void* ew  = d_in[1];
    const void* W1  = d_in[2];
    const void* b1  = d_in[3];
    const void* W2  = d_in[4];
    const void* b2  = d_in[5];
    const void* l1W = d_in[6];
    const void* l1b = d_in[7];
    const void* l2W = d_in[8];
    const void* l2b = d_in[9];
    const void* g1  = d_in[10];
    const void* bb1 = d_in[11];
    const void* g2  = d_in[12];
    const void* bb2 = d_in[13];
    const void* g3  = d_in[14];
    const void* bb3 = d_in[15];
    const int* eidx = (const int*)d_in[16];

    // common layout (float idx): flag 0, sums 16, dis 400, agg 100400,
    // hbuf(ushort) 6500400..9700400
    int*   flag = (int*)d_ws;
    float* wsf  = (float*)d_ws;
    float* sums = wsf + 16;
    float* dis  = wsf + 400;
    float* agg  = wsf + 100400;
    unsigned short* hbuf = (unsigned short*)(wsf + 6500400);

    // new path overlay: histmat 9700400 (+NSB*NBK=400384), btot 10100784 (+1024),
    // bstart 10101808 (+1024), packed 10102832 (+3.2M), wts 13302832 (+3.2M)
    int*      histmat = (int*)(wsf + 9700400);
    int*      btot    = (int*)(wsf + 10100784);
    int*      bstart  = (int*)(wsf + 10101808);
    unsigned* packed  = (unsigned*)(wsf + 10102832);
    float*    wts     = wsf + 13302832;
    const size_t NEED_NEW = (size_t)16502832 * 4;   // 66.0 MB

    // R3 fallback overlay (proven 65.2 MB)
    int*   rowptr   = (int*)(wsf + 9700400);
    int*   cursor   = (int*)(wsf + 9800400);
    int*   blocksum = (int*)(wsf + 9900400);
    int*   srcs     = (int*)(wsf + 9900912);
    float* coefs    = wsf + 13100912;
    const size_t NEED_CSR = (size_t)16300912 * 4;   // 65.2 MB

    if (ws_size < NEED_CSR) return;
    const bool fast = ws_size >= NEED_NEW;

    k_detect<<<1, 256, 0, stream>>>(x, eidx, flag);

    if (fast) {
        k_init  <<<391, 256, 0, stream>>>(dis, sums, nullptr);
        k_hist  <<<NSB, 256, 0, stream>>>(flag, eidx, histmat);
        k_scanA <<<NBK, 256, 0, stream>>>(histmat, btot);
        k_scanB <<<1, 1024, 0, stream>>>(btot, bstart);
        k_scatter<<<NSB, 256, 0, stream>>>(flag, eidx, ew, histmat, bstart, packed, wts);
        k_bucketdeg<<<NBK, 256, 0, stream>>>(bstart, packed, wts, dis);
        // layer 1
        k_gemm1 <<<1563, 256, 0, stream>>>(flag, x, W1, b1, dis, hbuf, nullptr);
        k_agg   <<<NBK, 256, 0, stream>>>(flag, bstart, packed, wts, dis, b1, hbuf, agg);
        k_bnstats<<<512, 256, 0, stream>>>(agg, sums + 0, 1);
        // layer 2
        k_gemm64<true, true><<<1563, 256, 0, stream>>>(flag, agg, W2, b2, g1, bb1,
                                                       sums + 0, dis, hbuf, nullptr, nullptr);
        k_agg   <<<NBK, 256, 0, stream>>>(flag, bstart, packed, wts, dis, b2, hbuf, agg);
    } else {
        k_init  <<<391, 256, 0, stream>>>(dis, sums, cursor);
        k_deg   <<<NE/256, 256, 0, stream>>>(flag, eidx, ew, dis, cursor);
        k_rsqrt <<<391, 256, 0, stream>>>(dis);
        k_scan1 <<<391, 256, 0, stream>>>(cursor, rowptr, blocksum);
        k_scan2 <<<1, 512, 0, stream>>>(blocksum);
        k_scan3 <<<391, 256, 0, stream>>>(rowptr, blocksum, cursor);
        k_fill  <<<NE/256, 256, 0, stream>>>(flag, eidx, ew, dis, cursor, srcs, coefs);
        k_gemm1 <<<1563, 256, 0, stream>>>(flag, x, W1, b1, dis, hbuf, nullptr);
        k_gather<<<NN/4, 256, 0, stream>>>(flag, rowptr, cursor, srcs, coefs,
                                           dis, b1, hbuf, agg);
        k_bnstats<<<512, 256, 0, stream>>>(agg, sums + 0, 1);
        k_gemm64<true, true><<<1563, 256, 0, stream>>>(flag, agg, W2, b2, g1, bb1,
                                                       sums + 0, dis, hbuf, nullptr, nullptr);
        k_gather<<<NN/4, 256, 0, stream>>>(flag, rowptr, cursor, srcs, coefs,
                                           dis, b2, hbuf, agg);
    }
    k_bnstats<<<512, 256, 0, stream>>>(agg, sums + 128, 0);
    k_gemm64<false, false><<<1563, 256, 0, stream>>>(flag, agg, l1W, l1b, g2, bb2,
                                                     sums + 128, dis, hbuf, agg, sums + 256);
    k_final <<<1563, 256, 0, stream>>>(flag, agg, g3, bb3, sums + 256, l2W, l2b, d_out);
}

// Round 5
// 741.992 us; speedup vs baseline: 4.3046x; 4.3046x over previous
//
#include <hip/hip_runtime.h>
#include <hip/hip_bf16.h>

// R5: R4's k_agg (782 blocks, latency-bound, 1382us) replaced by per-node CSR
// gather (100k waves, register accumulate — R3's winning structure) built with
// ZERO global atomics: LDS counting sort by bucket (R4) + new in-place
// per-bucket node sort (k_sort2, LDS-staged). rowptr overlays dead histmat so
// footprint == R4's proven 66,011,328 B.

#define NN 100000
#define NE 3200000
#define INV_N (1.0f/100000.0f)
#define BN_EPS 1e-5f
#define NBK 782            // buckets of 128 nodes
#define NSB 512            // scatter/hist blocks
#define EPB 6250           // edges per scatter/hist block (NSB*EPB == NE)
#define CAP 7424           // LDS staging capacity per bucket (mean 4092, 52 sigma)

static __device__ __forceinline__ float bf2f(unsigned short u) {
    if ((u & 0x7f80u) == 0x7f80u) u = 0;          // inf/NaN -> 0 (scrub)
    union { unsigned int i; float f; } z; z.i = ((unsigned int)u) << 16; return z.f;
}
static __device__ __forceinline__ float scrubf(float v) {
    return (fabsf(v) < 1e30f) ? v : 0.f;
}
static __device__ __forceinline__ unsigned short f2bf(float v) {
    union { float f; unsigned int i; } z; z.f = v;
    unsigned int lsb = (z.i >> 16) & 1u; z.i += 0x7fffu + lsb;
    return (unsigned short)(z.i >> 16);
}
static __device__ __forceinline__ float ld1(const void* p, size_t i, int f) {
    return f ? scrubf(((const float*)p)[i]) : bf2f(((const unsigned short*)p)[i]);
}
static __device__ __forceinline__ float4 ld4(const void* p, size_t g, int f) {
    if (f) { float4 v = ((const float4*)p)[g];
             return make_float4(scrubf(v.x),scrubf(v.y),scrubf(v.z),scrubf(v.w)); }
    ushort4 u = ((const ushort4*)p)[g];
    return make_float4(bf2f(u.x),bf2f(u.y),bf2f(u.z),bf2f(u.w));
}
static __device__ __forceinline__ int getidx(const int* ei, size_t pos, int i64) {
    return i64 ? ei[2*pos] : ei[pos];
}

// ---------------- dtype / index-width detector ----------------
__global__ void k_detect(const unsigned short* __restrict__ x,
                         const int* __restrict__ ei, int* __restrict__ flag) {
    __shared__ int cnt[256];
    int tid = threadIdx.x, c = 0;
    for (int i = tid; i < 1024; i += 256) {
        unsigned short u = x[i];
        int ex = (u >> 7) & 0xff;
        if ((u & 0x7fffu) != 0 && (ex >= 0xB0 || ex <= 0x40)) c++;
    }
    cnt[tid] = c; __syncthreads();
    if (tid == 0) { int t = 0; for (int i = 0; i < 256; ++i) t += cnt[i];
                    flag[0] = (t > 64) ? 1 : 0; }
    if (tid == 1) { int nz = 0; for (int i = 1; i < 64; i += 2) nz |= ei[i];
                    flag[1] = (nz == 0) ? 1 : 0; }
}

__global__ void k_init(float* __restrict__ dis, float* __restrict__ sums,
                       int* __restrict__ cnt) {
    int i = blockIdx.x * 256 + threadIdx.x;
    if (i < NN)  dis[i] = 1.0f;
    if (i < 384) sums[i] = 0.0f;
    if (cnt && i < NN) cnt[i] = 0;
}

// ================= bucket counting sort (no global atomics) =================

__global__ __launch_bounds__(256) void k_hist(const int* __restrict__ flag,
                                              const int* __restrict__ ei,
                                              int* __restrict__ histmat) {
    __shared__ int hh[NBK];
    const int i64 = flag[1];
    const int blk = blockIdx.x, tid = threadIdx.x;
    for (int b = tid; b < NBK; b += 256) hh[b] = 0;
    __syncthreads();
    const size_t e0 = (size_t)blk * EPB;
    for (int e = tid; e < EPB; e += 256) {
        unsigned d = (unsigned)getidx(ei, NE + e0 + e, i64);
        if (d < NN) atomicAdd(&hh[d >> 7], 1);
    }
    __syncthreads();
    for (int b = tid; b < NBK; b += 256) histmat[blk*NBK + b] = hh[b];
}

__global__ __launch_bounds__(256) void k_scanA(int* __restrict__ histmat,
                                               int* __restrict__ btot) {
    __shared__ int sd[256];
    const int b = blockIdx.x, t = threadIdx.x;
    int v0 = histmat[(2*t)*NBK + b];
    int v1 = histmat[(2*t+1)*NBK + b];
    int ts = v0 + v1;
    sd[t] = ts; __syncthreads();
    #pragma unroll
    for (int ofs = 1; ofs < 256; ofs <<= 1) {
        int a = (t >= ofs) ? sd[t-ofs] : 0;
        __syncthreads(); sd[t] += a; __syncthreads();
    }
    int excl = sd[t] - ts;
    histmat[(2*t)*NBK + b]   = excl;
    histmat[(2*t+1)*NBK + b] = excl + v0;
    if (t == 255) btot[b] = sd[255];
}

__global__ void k_scanB(const int* __restrict__ btot, int* __restrict__ bstart) {
    __shared__ int sd[1024];
    int t = threadIdx.x;                 // 1024 threads
    int v = (t < NBK) ? btot[t] : 0;
    sd[t] = v; __syncthreads();
    #pragma unroll
    for (int ofs = 1; ofs < 1024; ofs <<= 1) {
        int a = (t >= ofs) ? sd[t-ofs] : 0;
        __syncthreads(); sd[t] += a; __syncthreads();
    }
    if (t <= NBK) bstart[t] = sd[t] - v;   // bstart[NBK] = total
}

__global__ __launch_bounds__(256) void k_scatter(
    const int* __restrict__ flag, const int* __restrict__ ei,
    const void* __restrict__ ew, const int* __restrict__ histmat,
    const int* __restrict__ bstart, unsigned* __restrict__ packed,
    float* __restrict__ wts) {
    __shared__ int cursor[NBK];
    const int f = flag[0], i64 = flag[1];
    const int blk = blockIdx.x, tid = threadIdx.x;
    for (int b = tid; b < NBK; b += 256)
        cursor[b] = histmat[blk*NBK + b] + bstart[b];
    __syncthreads();
    const size_t e0 = (size_t)blk * EPB;
    for (int e = tid; e < EPB; e += 256) {
        unsigned d = (unsigned)getidx(ei, NE + e0 + e, i64);
        if (d >= NN) continue;
        unsigned s = (unsigned)getidx(ei, e0 + e, i64);
        float w = ld1(ew, e0 + e, f);
        if (s >= NN) { s = 0; w = 0.f; }
        int pos = atomicAdd(&cursor[d >> 7], 1);
        packed[pos] = ((d & 127u) << 17) | s;
        wts[pos] = w;
    }
}

__global__ __launch_bounds__(256) void k_bucketdeg(
    const int* __restrict__ bstart, const unsigned* __restrict__ packed,
    const float* __restrict__ wts, float* __restrict__ dis) {
    __shared__ float degf[128];
    const int b = blockIdx.x, tid = threadIdx.x;
    if (tid < 128) degf[tid] = 1.0f;
    __syncthreads();
    const int r0 = bstart[b], r1 = bstart[b+1];
    for (int j = r0 + tid; j < r1; j += 256)
        atomicAdd(&degf[(packed[j] >> 17) & 127], wts[j]);
    __syncthreads();
    if (tid < 128) {
        int node = b*128 + tid;
        if (node < NN) dis[node] = rsqrtf(fmaxf(degf[tid], 1e-12f));
    }
}

// per-bucket in-place node sort: packed -> src, wts -> coef, rowptr written.
// Overflow bucket (> CAP, never for this dataset): rowptr = -(b+1) sentinel.
__global__ __launch_bounds__(256) void k_sort2(
    const int* __restrict__ bstart, const float* __restrict__ dis,
    unsigned* __restrict__ packed, float* __restrict__ wts,
    int* __restrict__ rowptr) {
    __shared__ unsigned sp[CAP];
    __shared__ float    sw[CAP];
    __shared__ int cnt[128], scn[128], cur[128];
    __shared__ float disloc[128];
    const int b = blockIdx.x, tid = threadIdx.x;
    const int node0 = b * 128;
    const int r0 = bstart[b], r1 = bstart[b+1], n = r1 - r0;

    if (tid < 128) {
        int node = node0 + tid;
        disloc[tid] = (node < NN) ? dis[node] : 0.f;
        cnt[tid] = 0;
    }
    __syncthreads();
    if (n > CAP) {                                // correct-but-slow sentinel
        if (tid < 128 && node0 + tid < NN) rowptr[node0 + tid] = -(b + 1);
        return;
    }
    for (int j = tid; j < n; j += 256) {
        unsigned p = packed[r0 + j];
        sp[j] = p; sw[j] = wts[r0 + j];
        atomicAdd(&cnt[(p >> 17) & 127], 1);
    }
    __syncthreads();
    if (tid < 128) scn[tid] = cnt[tid];
    __syncthreads();
    #pragma unroll
    for (int ofs = 1; ofs < 128; ofs <<= 1) {
        int a = 0;
        if (tid < 128 && tid >= ofs) a = scn[tid - ofs];
        __syncthreads();
        if (tid < 128) scn[tid] += a;
        __syncthreads();
    }
    if (tid < 128) {
        int excl = scn[tid] - cnt[tid];
        cur[tid] = excl;
        if (node0 + tid <= NN) rowptr[node0 + tid] = r0 + excl;  // end via neighbor
    }
    __syncthreads();
    for (int j = tid; j < n; j += 256) {
        unsigned p = sp[j];
        int l = (p >> 17) & 127;
        unsigned s = p & 0x1ffffu;
        int pos = atomicAdd(&cur[l], 1);
        packed[r0 + pos] = s;
        wts[r0 + pos] = sw[j] * dis[s] * disloc[l];
    }
}

// wave per node, register accumulate (R3 structure, zero-atomic CSR)
__global__ __launch_bounds__(256) void k_gather2(
    const int* __restrict__ flag, const int* __restrict__ rowptr,
    const int* __restrict__ bstart, const unsigned* __restrict__ srcs,
    const float* __restrict__ coefs, const float* __restrict__ dis,
    const void* __restrict__ bias, const unsigned short* __restrict__ h,
    float* __restrict__ agg) {
    const int f = flag[0];
    int node = blockIdx.x * 4 + (threadIdx.x >> 6);   // grid exact: NN/4
    int lane = threadIdx.x & 63;
    float d2 = dis[node];
    float acc = ld1(bias, lane, f) + d2*d2*bf2f(h[(size_t)node*64 + lane]);
    int rp = rowptr[node];
    if (rp >= 0) {
        int l = node & 127;
        int end = (l == 127) ? bstart[(node >> 7) + 1] : rowptr[node + 1];
        int j = rp;
        for (; j + 4 <= end; j += 4) {
            unsigned s0 = srcs[j],  s1 = srcs[j+1];
            unsigned s2 = srcs[j+2], s3 = srcs[j+3];
            float c0 = coefs[j],   c1 = coefs[j+1];
            float c2 = coefs[j+2], c3 = coefs[j+3];
            acc = fmaf(c0, bf2f(h[(size_t)s0*64+lane]), acc);
            acc = fmaf(c1, bf2f(h[(size_t)s1*64+lane]), acc);
            acc = fmaf(c2, bf2f(h[(size_t)s2*64+lane]), acc);
            acc = fmaf(c3, bf2f(h[(size_t)s3*64+lane]), acc);
        }
        for (; j < end; ++j)
            acc = fmaf(coefs[j], bf2f(h[(size_t)srcs[j]*64 + lane]), acc);
    } else {                                          // overflow bucket scan
        int b = node >> 7, l = node & 127;
        for (int j = bstart[b]; j < bstart[b+1]; ++j) {
            unsigned p = srcs[j];
            if (((int)(p >> 17) & 127) == l) {
                unsigned s = p & 0x1ffffu;
                acc = fmaf(coefs[j] * dis[s] * d2, bf2f(h[(size_t)s*64+lane]), acc);
            }
        }
    }
    agg[(size_t)node*64 + lane] = acc;
}

// ================= FALLBACK (R3) kernels =================

__global__ void k_deg(const int* __restrict__ flag, const int* __restrict__ ei,
                      const void* __restrict__ ew, float* __restrict__ deg,
                      int* __restrict__ cnt) {
    const int f = flag[0], i64 = flag[1];
    int e = blockIdx.x * 256 + threadIdx.x;
    unsigned d = (unsigned)getidx(ei, NE + (size_t)e, i64);
    if (d < NN) {
        unsafeAtomicAdd(&deg[d], ld1(ew, e, f));
        if (cnt) atomicAdd(&cnt[d], 1);
    }
}
__global__ void k_rsqrt(float* __restrict__ dis) {
    int i = blockIdx.x * 256 + threadIdx.x;
    if (i < NN) dis[i] = rsqrtf(fmaxf(dis[i], 1e-12f));
}
__global__ void k_scan1(const int* __restrict__ cnt, int* __restrict__ rowptr,
                        int* __restrict__ blocksum) {
    __shared__ int sd[256];
    int t = threadIdx.x, i = blockIdx.x*256 + t;
    int v = (i < NN) ? cnt[i] : 0;
    sd[t] = v; __syncthreads();
    #pragma unroll
    for (int ofs = 1; ofs < 256; ofs <<= 1) {
        int a = (t >= ofs) ? sd[t-ofs] : 0;
        __syncthreads(); sd[t] += a; __syncthreads();
    }
    if (i < NN) rowptr[i] = sd[t] - v;
    if (t == 255) blocksum[blockIdx.x] = sd[255];
}
__global__ void k_scan2(int* __restrict__ blocksum) {
    __shared__ int sd[512];
    int t = threadIdx.x;
    int v = (t < 391) ? blocksum[t] : 0;
    sd[t] = v; __syncthreads();
    #pragma unroll
    for (int ofs = 1; ofs < 512; ofs <<= 1) {
        int a = (t >= ofs) ? sd[t-ofs] : 0;
        __syncthreads(); sd[t] += a; __syncthreads();
    }
    if (t < 391) blocksum[t] = sd[t] - v;
}
__global__ void k_scan3(int* __restrict__ rowptr, const int* __restrict__ blocksum,
                        int* __restrict__ cursor) {
    int i = blockIdx.x*256 + threadIdx.x;
    if (i < NN) { int r = rowptr[i] + blocksum[blockIdx.x]; rowptr[i] = r; cursor[i] = r; }
}
__global__ void k_fill(const int* __restrict__ flag, const int* __restrict__ ei,
                       const void* __restrict__ ew, const float* __restrict__ dis,
                       int* __restrict__ cursor, int* __restrict__ srcs,
                       float* __restrict__ coefs) {
    const int f = flag[0], i64 = flag[1];
    int e = blockIdx.x * 256 + threadIdx.x;
    unsigned s = (unsigned)getidx(ei, (size_t)e, i64);
    unsigned d = (unsigned)getidx(ei, NE + (size_t)e, i64);
    if (s >= NN || d >= NN) return;
    float coef = dis[s] * ld1(ew, e, f) * dis[d];
    int pos = atomicAdd(&cursor[d], 1);
    srcs[pos] = (int)s;
    coefs[pos] = coef;
}
__global__ __launch_bounds__(256) void k_gather(
    const int* __restrict__ flag, const int* __restrict__ rowptr,
    const int* __restrict__ rowend, const int* __restrict__ srcs,
    const float* __restrict__ coefs, const float* __restrict__ dis,
    const void* __restrict__ bias, const unsigned short* __restrict__ h,
    float* __restrict__ agg) {
    const int f = flag[0];
    int node = blockIdx.x * 4 + (threadIdx.x >> 6);
    int lane = threadIdx.x & 63;
    float d2 = dis[node];
    float acc = ld1(bias, lane, f) + d2*d2*bf2f(h[(size_t)node*64 + lane]);
    int j = rowptr[node], end = rowend[node];
    for (; j < end; ++j)
        acc = fmaf(coefs[j], bf2f(h[(size_t)srcs[j]*64 + lane]), acc);
    agg[(size_t)node*64 + lane] = acc;
}

// ================= dense kernels =================

__global__ __launch_bounds__(256) void k_gemm1(
    const int* __restrict__ flag, const void* __restrict__ x,
    const void* __restrict__ W, const void* __restrict__ bias,
    const float* __restrict__ dis,
    unsigned short* __restrict__ h_out, float* __restrict__ agg_out) {
    __shared__ __align__(16) float ws[128*64];
    __shared__ __align__(16) float xs[64*64];
    const int f = flag[0];
    const int tid = threadIdx.x;
    const int rowbase = blockIdx.x * 64;
    #pragma unroll
    for (int it = 0; it < 8; ++it) {
        int g = it*256 + tid;
        float4 v = ld4(W, g, f);
        int b = g*4;
        ws[b]=v.x; ws[b+1]=v.y; ws[b+2]=v.z; ws[b+3]=v.w;
    }
    const int tr = (tid >> 4) << 2;
    const int tc = (tid & 15) << 2;
    const int row = tid & 63;
    const int grow = rowbase + row;
    const bool valid = grow < NN;
    float acc[4][4] = {};
    for (int half = 0; half < 2; ++half) {
        __syncthreads();
        #pragma unroll
        for (int it = 0; it < 4; ++it) {
            int f4 = (tid >> 6) + it*4;
            int kl = f4*4;
            float4 v = make_float4(0,0,0,0);
            if (valid) v = ld4(x, (size_t)grow*32 + half*16 + f4, f);
            xs[(kl+0)*64+row]=v.x; xs[(kl+1)*64+row]=v.y;
            xs[(kl+2)*64+row]=v.z; xs[(kl+3)*64+row]=v.w;
        }
        __syncthreads();
        #pragma unroll 8
        for (int k = 0; k < 64; ++k) {
            const float4 av = *(const float4*)&xs[k*64 + tr];
            const float4 wv = *(const float4*)&ws[(half*64 + k)*64 + tc];
            const float aa[4] = {av.x, av.y, av.z, av.w};
            const float ww[4] = {wv.x, wv.y, wv.z, wv.w};
            #pragma unroll
            for (int i = 0; i < 4; ++i)
                #pragma unroll
                for (int j = 0; j < 4; ++j)
                    acc[i][j] = fmaf(aa[i], ww[j], acc[i][j]);
        }
    }
    float bc[4];
    #pragma unroll
    for (int j = 0; j < 4; ++j) bc[j] = ld1(bias, tc+j, f);
    #pragma unroll
    for (int i = 0; i < 4; ++i) {
        int r = rowbase + tr + i;
        if (r < NN) {
            ushort4 hv = make_ushort4(f2bf(acc[i][0]), f2bf(acc[i][1]),
                                      f2bf(acc[i][2]), f2bf(acc[i][3]));
            *(ushort4*)&h_out[(size_t)r*64 + tc] = hv;
            if (agg_out) {
                float dd = dis[r]; float idg = dd*dd;
                *(float4*)&agg_out[(size_t)r*64 + tc] =
                    make_float4(acc[i][0]*idg+bc[0], acc[i][1]*idg+bc[1],
                                acc[i][2]*idg+bc[2], acc[i][3]*idg+bc[3]);
            }
        }
    }
}

__global__ __launch_bounds__(256) void k_bnstats(const float* __restrict__ src,
                                                 float* __restrict__ sumout, int relu) {
    const int tid = threadIdx.x;
    float s = 0.f, q = 0.f;
    for (int i = blockIdx.x*256 + tid; i < NN*64; i += 512*256) {
        float v = src[i];
        if (relu) v = fmaxf(v, 0.f);
        s += v; q += v*v;
    }
    __shared__ float ls[256], lq[256];
    ls[tid] = s; lq[tid] = q;
    __syncthreads();
    if (tid < 64) {
        s = ls[tid]+ls[tid+64]+ls[tid+128]+ls[tid+192];
        q = lq[tid]+lq[tid+64]+lq[tid+128]+lq[tid+192];
        unsafeAtomicAdd(&sumout[tid], s);
        unsafeAtomicAdd(&sumout[64+tid], q);
    }
}

template<bool RELU, bool AGG>
__global__ __launch_bounds__(256) void k_gemm64(
    const int* __restrict__ flag, const float* __restrict__ in,
    const void* __restrict__ W, const void* __restrict__ bias,
    const void* __restrict__ g, const void* __restrict__ bb,
    const float* __restrict__ insums, const float* __restrict__ dis,
    unsigned short* __restrict__ h_out, float* __restrict__ y_out,
    float* __restrict__ outsums) {
    __shared__ __align__(16) float ws[64*64];
    __shared__ __align__(16) float xs[64*64];
    __shared__ float sc[64], sh[64];
    const int f = flag[0];
    const int tid = threadIdx.x;
    const int rowbase = blockIdx.x * 64;
    if (tid < 64) {
        float mean = insums[tid] * INV_N;
        float var  = fmaxf(insums[64+tid] * INV_N - mean*mean, 0.f);
        float s = ld1(g, tid, f) * rsqrtf(var + BN_EPS);
        sc[tid] = s;
        sh[tid] = ld1(bb, tid, f) - mean*s;
    }
    #pragma unroll
    for (int it = 0; it < 4; ++it) {
        int gi = it*256 + tid;
        float4 v = ld4(W, gi, f);
        int b = gi*4;
        ws[b]=v.x; ws[b+1]=v.y; ws[b+2]=v.z; ws[b+3]=v.w;
    }
    __syncthreads();
    {
        int row = tid & 63;
        int grow = rowbase + row;
        bool valid = grow < NN;
        #pragma unroll
        for (int it = 0; it < 4; ++it) {
            int f4 = (tid >> 6) + it*4;
            int k = f4*4;
            float4 v = make_float4(0,0,0,0);
            if (valid) v = *(const float4*)&in[(size_t)grow*64 + k];
            float a0=v.x, a1=v.y, a2=v.z, a3=v.w;
            if (RELU) { a0=fmaxf(a0,0.f); a1=fmaxf(a1,0.f); a2=fmaxf(a2,0.f); a3=fmaxf(a3,0.f); }
            a0 = a0*sc[k+0]+sh[k+0]; a1 = a1*sc[k+1]+sh[k+1];
            a2 = a2*sc[k+2]+sh[k+2]; a3 = a3*sc[k+3]+sh[k+3];
            xs[(k+0)*64+row]=a0; xs[(k+1)*64+row]=a1;
            xs[(k+2)*64+row]=a2; xs[(k+3)*64+row]=a3;
        }
    }
    __syncthreads();
    const int tr = (tid >> 4) << 2;
    const int tc = (tid & 15) << 2;
    float acc[4][4] = {};
    #pragma unroll 8
    for (int k = 0; k < 64; ++k) {
        const float4 av = *(const float4*)&xs[k*64 + tr];
        const float4 wv = *(const float4*)&ws[k*64 + tc];
        const float aa[4] = {av.x, av.y, av.z, av.w};
        const float ww[4] = {wv.x, wv.y, wv.z, wv.w};
        #pragma unroll
        for (int i = 0; i < 4; ++i)
            #pragma unroll
            for (int j = 0; j < 4; ++j)
                acc[i][j] = fmaf(aa[i], ww[j], acc[i][j]);
    }
    float bc[4];
    #pragma unroll
    for (int j = 0; j < 4; ++j) bc[j] = ld1(bias, tc+j, f);
    if (AGG) {
        #pragma unroll
        for (int i = 0; i < 4; ++i) {
            int r = rowbase + tr + i;
            if (r < NN) {
                ushort4 hv = make_ushort4(f2bf(acc[i][0]), f2bf(acc[i][1]),
                                          f2bf(acc[i][2]), f2bf(acc[i][3]));
                *(ushort4*)&h_out[(size_t)r*64 + tc] = hv;
                if (y_out) {
                    float dd = dis[r]; float idg = dd*dd;
                    *(float4*)&y_out[(size_t)r*64 + tc] =
                        make_float4(acc[i][0]*idg+bc[0], acc[i][1]*idg+bc[1],
                                    acc[i][2]*idg+bc[2], acc[i][3]*idg+bc[3]);
                }
            }
        }
    } else {
        float ps[4] = {0,0,0,0}, pq[4] = {0,0,0,0};
        #pragma unroll
        for (int i = 0; i < 4; ++i) {
            int r = rowbase + tr + i;
            if (r < NN) {
                float y0 = acc[i][0]+bc[0], y1 = acc[i][1]+bc[1];
                float y2 = acc[i][2]+bc[2], y3 = acc[i][3]+bc[3];
                *(float4*)&y_out[(size_t)r*64 + tc] = make_float4(y0,y1,y2,y3);
                ps[0]+=y0; ps[1]+=y1; ps[2]+=y2; ps[3]+=y3;
                pq[0]+=y0*y0; pq[1]+=y1*y1; pq[2]+=y2*y2; pq[3]+=y3*y3;
            }
        }
        __syncthreads();
        int grp = tid >> 4;
        #pragma unroll
        for (int j = 0; j < 4; ++j) { xs[grp*64 + tc+j] = ps[j]; ws[grp*64 + tc+j] = pq[j]; }
        __syncthreads();
        if (tid < 64) {
            float s = 0.f, q = 0.f;
            #pragma unroll
            for (int g2 = 0; g2 < 16; ++g2) { s += xs[g2*64+tid]; q += ws[g2*64+tid]; }
            unsafeAtomicAdd(&outsums[tid], s);
            unsafeAtomicAdd(&outsums[64+tid], q);
        }
    }
}

__global__ __launch_bounds__(256) void k_final(
    const int* __restrict__ flag, const float* __restrict__ y3,
    const void* __restrict__ g, const void* __restrict__ bb,
    const float* __restrict__ sums, const void* __restrict__ w2,
    const void* __restrict__ b2, void* __restrict__ out) {
    __shared__ __align__(16) float tile[64*64];
    __shared__ float wp[64], tv[64];
    const int f = flag[0];
    const int tid = threadIdx.x;
    const int base = blockIdx.x * 64;
    if (tid < 64) {
        float mean = sums[tid] * INV_N;
        float var  = fmaxf(sums[64+tid] * INV_N - mean*mean, 0.f);
        float s = ld1(g, tid, f) * rsqrtf(var + BN_EPS);
        float t = ld1(bb, tid, f) - mean*s;
        float w = ld1(w2, tid, f);
        wp[tid] = s*w; tv[tid] = t*w;
    }
    #pragma unroll
    for (int it = 0; it < 4; ++it) {
        int i4 = it*256 + tid;
        int row = i4 >> 4;
        float4 v = make_float4(0,0,0,0);
        if (base + row < NN) v = *(const float4*)&y3[(size_t)base*64 + i4*4];
        *(float4*)&tile[i4*4] = v;
    }
    __syncthreads();
    if (tid < 64 && base + tid < NN) {
        float a = ld1(b2, 0, f);
        #pragma unroll
        for (int c = 0; c < 64; ++c) a += tv[c];
        #pragma unroll
        for (int cc = 0; cc < 64; ++cc) {
            int c = (cc + tid) & 63;
            a += tile[tid*64 + c] * wp[c];
        }
        if (f) ((float*)out)[base + tid] = a;
        else   ((unsigned short*)out)[base + tid] = f2bf(a);
    }
}

extern "C" void kernel_launch(void* const* d_in, const int* in_sizes, int n_in,
                              void* d_out, int out_size, void* d_ws, size_t ws_size,
                              hipStream_t stream) {
    const unsigned short* x = (const unsigned short*)d_in[0];
    const void* ew  = d_in[1];
    const void* W1  = d_in[2];
    const void* b1  = d_in[3];
    const void* W2  = d_in[4];
    const void* b2  = d_in[5];
    const void* l1W = d_in[6];
    const void* l1b = d_in[7];
    const void* l2W = d_in[8];
    const void* l2b = d_in[9];
    const void* g1  = d_in[10];
    const void* bb1 = d_in[11];
    const void* g2  = d_in[12];
    const void* bb2 = d_in[13];
    const void* g3  = d_in[14];
    const void* bb3 = d_in[15];
    const int* eidx = (const int*)d_in[16];

    // common layout (float idx): flag 0, sums 16, dis 400, agg 100400,
    // hbuf(ushort) 6500400..9700400
    int*   flag = (int*)d_ws;
    float* wsf  = (float*)d_ws;
    float* sums = wsf + 16;
    float* dis  = wsf + 400;
    float* agg  = wsf + 100400;
    unsigned short* hbuf = (unsigned short*)(wsf + 6500400);

    // fast-path overlay (== R4's proven 66,011,328 B):
    // histmat 9700400 (400,384 ints; reused as rowptr after k_scatter),
    // btot 10100784, bstart 10101808, packed 10102832, wts 13302832
    int*      histmat = (int*)(wsf + 9700400);
    int*      rowptr2 = histmat;                    // overlay (histmat dead after scatter)
    int*      btot    = (int*)(wsf + 10100784);
    int*      bstart  = (int*)(wsf + 10101808);
    unsigned* packed  = (unsigned*)(wsf + 10102832);
    float*    wts     = wsf + 13302832;
    const size_t NEED_NEW = (size_t)16502832 * 4;   // 66.0 MB — proven by R4 run

    // R3 fallback overlay
    int*   rowptr   = (int*)(wsf + 9700400);
    int*   cursor   = (int*)(wsf + 9800400);
    int*   blocksum = (int*)(wsf + 9900400);
    int*   srcs     = (int*)(wsf + 9900912);
    float* coefs    = wsf + 13100912;
    const size_t NEED_CSR = (size_t)16300912 * 4;

    if (ws_size < NEED_CSR) return;
    const bool fast = ws_size >= NEED_NEW;

    k_detect<<<1, 256, 0, stream>>>(x, eidx, flag);

    if (fast) {
        k_init     <<<391, 256, 0, stream>>>(dis, sums, nullptr);
        k_hist     <<<NSB, 256, 0, stream>>>(flag, eidx, histmat);
        k_scanA    <<<NBK, 256, 0, stream>>>(histmat, btot);
        k_scanB    <<<1, 1024, 0, stream>>>(btot, bstart);
        k_scatter  <<<NSB, 256, 0, stream>>>(flag, eidx, ew, histmat, bstart, packed, wts);
        k_bucketdeg<<<NBK, 256, 0, stream>>>(bstart, packed, wts, dis);
        k_sort2    <<<NBK, 256, 0, stream>>>(bstart, dis, packed, wts, rowptr2);
        // layer 1
        k_gemm1    <<<1563, 256, 0, stream>>>(flag, x, W1, b1, dis, hbuf, nullptr);
        k_gather2  <<<NN/4, 256, 0, stream>>>(flag, rowptr2, bstart, packed, wts,
                                              dis, b1, hbuf, agg);
        k_bnstats  <<<512, 256, 0, stream>>>(agg, sums + 0, 1);
        // layer 2
        k_gemm64<true, true><<<1563, 256, 0, stream>>>(flag, agg, W2, b2, g1, bb1,
                                                       sums + 0, dis, hbuf, nullptr, nullptr);
        k_gather2  <<<NN/4, 256, 0, stream>>>(flag, rowptr2, bstart, packed, wts,
                                              dis, b2, hbuf, agg);
    } else {
        k_init  <<<391, 256, 0, stream>>>(dis, sums, cursor);
        k_deg   <<<NE/256, 256, 0, stream>>>(flag, eidx, ew, dis, cursor);
        k_rsqrt <<<391, 256, 0, stream>>>(dis);
        k_scan1 <<<391, 256, 0, stream>>>(cursor, rowptr, blocksum);
        k_scan2 <<<1, 512, 0, stream>>>(blocksum);
        k_scan3 <<<391, 256, 0, stream>>>(rowptr, blocksum, cursor);
        k_fill  <<<NE/256, 256, 0, stream>>>(flag, eidx, ew, dis, cursor, srcs, coefs);
        k_gemm1 <<<1563, 256, 0, stream>>>(flag, x, W1, b1, dis, hbuf, nullptr);
        k_gather<<<NN/4, 256, 0, stream>>>(flag, rowptr, cursor, srcs, coefs,
                                           dis, b1, hbuf, agg);
        k_bnstats<<<512, 256, 0, stream>>>(agg, sums + 0, 1);
        k_gemm64<true, true><<<1563, 256, 0, stream>>>(flag, agg, W2, b2, g1, bb1,
                                                       sums + 0, dis, hbuf, nullptr, nullptr);
        k_gather<<<NN/4, 256, 0, stream>>>(flag, rowptr, cursor, srcs, coefs,
                                           dis, b2, hbuf, agg);
    }
    k_bnstats<<<512, 256, 0, stream>>>(agg, sums + 128, 0);
    k_gemm64<false, false><<<1563, 256, 0, stream>>>(flag, agg, l1W, l1b, g2, bb2,
                                                     sums + 128, dis, hbuf, agg, sums + 256);
    k_final <<<1563, 256, 0, stream>>>(flag, agg, g3, bb3, sums + 256, l2W, l2b, d_out);
}

// Round 6
// 697.115 us; speedup vs baseline: 4.5817x; 1.0644x over previous
//
#include <hip/hip_runtime.h>
#include <hip/hip_bf16.h>

// R6: gather2 restructured to 2-edges-per-wave (lanes 0-31 edge j, 32-63 edge
// j+1; uint loads unpack 2 bf16 features; shfl_xor(32) merge) -> ~2x fewer
// VALU ops per edge. Edge metadata interleaved int2 (src,coef). Scratch for
// unsorted edges lives in the agg region, so ws need == R4/R5's proven
// 66,011,328 B. Dispatch count 16 -> 14.

#define NN 100000
#define NE 3200000
#define INV_N (1.0f/100000.0f)
#define BN_EPS 1e-5f
#define NBK 782            // buckets of 128 nodes
#define NSB 512            // scatter/hist blocks
#define EPB 6250           // edges per scatter/hist block (NSB*EPB == NE)
#define CAP 7424           // LDS staging capacity per bucket (mean 4092, 52 sigma)

static __device__ __forceinline__ float bf2f(unsigned short u) {
    if ((u & 0x7f80u) == 0x7f80u) u = 0;          // inf/NaN -> 0 (input scrub)
    union { unsigned int i; float f; } z; z.i = ((unsigned int)u) << 16; return z.f;
}
static __device__ __forceinline__ float scrubf(float v) {
    return (fabsf(v) < 1e30f) ? v : 0.f;
}
static __device__ __forceinline__ unsigned short f2bf(float v) {
    union { float f; unsigned int i; } z; z.f = v;
    unsigned int lsb = (z.i >> 16) & 1u; z.i += 0x7fffu + lsb;
    return (unsigned short)(z.i >> 16);
}
static __device__ __forceinline__ float ld1(const void* p, size_t i, int f) {
    return f ? scrubf(((const float*)p)[i]) : bf2f(((const unsigned short*)p)[i]);
}
static __device__ __forceinline__ float4 ld4(const void* p, size_t g, int f) {
    if (f) { float4 v = ((const float4*)p)[g];
             return make_float4(scrubf(v.x),scrubf(v.y),scrubf(v.z),scrubf(v.w)); }
    ushort4 u = ((const ushort4*)p)[g];
    return make_float4(bf2f(u.x),bf2f(u.y),bf2f(u.z),bf2f(u.w));
}
static __device__ __forceinline__ int getidx(const int* ei, size_t pos, int i64) {
    return i64 ? ei[2*pos] : ei[pos];
}
static __device__ __forceinline__ float blo(unsigned v) {
    union { unsigned u; float f; } z; z.u = v << 16; return z.f;
}
static __device__ __forceinline__ float bhi(unsigned v) {
    union { unsigned u; float f; } z; z.u = v & 0xffff0000u; return z.f;
}

// ---------------- detector + sums zero ----------------
__global__ void k_detect2(const unsigned short* __restrict__ x,
                          const int* __restrict__ ei, int* __restrict__ flag,
                          float* __restrict__ sums) {
    __shared__ int cnt[256];
    int tid = threadIdx.x, c = 0;
    for (int i = tid; i < 1024; i += 256) {
        unsigned short u = x[i];
        int ex = (u >> 7) & 0xff;
        if ((u & 0x7fffu) != 0 && (ex >= 0xB0 || ex <= 0x40)) c++;
    }
    cnt[tid] = c; __syncthreads();
    if (tid == 0) { int t = 0; for (int i = 0; i < 256; ++i) t += cnt[i];
                    flag[0] = (t > 64) ? 1 : 0; }
    if (tid == 1) { int nz = 0; for (int i = 1; i < 64; i += 2) nz |= ei[i];
                    flag[1] = (nz == 0) ? 1 : 0; }
    if (tid < 128) { sums[tid]=0.f; sums[128+tid]=0.f; sums[256+tid]=0.f; }
}

// ================= bucket counting sort (no global atomics) =================

__global__ __launch_bounds__(256) void k_hist(const int* __restrict__ flag,
                                              const int* __restrict__ ei,
                                              int* __restrict__ histmat) {
    __shared__ int hh[NBK];
    const int i64 = flag[1];
    const int blk = blockIdx.x, tid = threadIdx.x;
    for (int b = tid; b < NBK; b += 256) hh[b] = 0;
    __syncthreads();
    const size_t e0 = (size_t)blk * EPB;
    for (int e = tid; e < EPB; e += 256) {
        unsigned d = (unsigned)getidx(ei, NE + e0 + e, i64);
        if (d < NN) atomicAdd(&hh[d >> 7], 1);
    }
    __syncthreads();
    for (int b = tid; b < NBK; b += 256) histmat[blk*NBK + b] = hh[b];
}

__global__ __launch_bounds__(256) void k_scanA(int* __restrict__ histmat,
                                               int* __restrict__ btot) {
    __shared__ int sd[256];
    const int b = blockIdx.x, t = threadIdx.x;
    int v0 = histmat[(2*t)*NBK + b];
    int v1 = histmat[(2*t+1)*NBK + b];
    int ts = v0 + v1;
    sd[t] = ts; __syncthreads();
    #pragma unroll
    for (int ofs = 1; ofs < 256; ofs <<= 1) {
        int a = (t >= ofs) ? sd[t-ofs] : 0;
        __syncthreads(); sd[t] += a; __syncthreads();
    }
    int excl = sd[t] - ts;
    histmat[(2*t)*NBK + b]   = excl;
    histmat[(2*t+1)*NBK + b] = excl + v0;
    if (t == 255) btot[b] = sd[255];
}

__global__ void k_scanB(const int* __restrict__ btot, int* __restrict__ bstart) {
    __shared__ int sd[1024];
    int t = threadIdx.x;                 // 1024 threads
    int v = (t < NBK) ? btot[t] : 0;
    sd[t] = v; __syncthreads();
    #pragma unroll
    for (int ofs = 1; ofs < 1024; ofs <<= 1) {
        int a = (t >= ofs) ? sd[t-ofs] : 0;
        __syncthreads(); sd[t] += a; __syncthreads();
    }
    if (t <= NBK) bstart[t] = sd[t] - v;   // bstart[NBK] = total
}

// scatter edges -> scratch (bucket-grouped int2 {dloc<<17|src, w}); LDS atomics only
__global__ __launch_bounds__(256) void k_scatter(
    const int* __restrict__ flag, const int* __restrict__ ei,
    const void* __restrict__ ew, const int* __restrict__ histmat,
    const int* __restrict__ bstart, int2* __restrict__ scr) {
    __shared__ int cursor[NBK];
    const int f = flag[0], i64 = flag[1];
    const int blk = blockIdx.x, tid = threadIdx.x;
    for (int b = tid; b < NBK; b += 256)
        cursor[b] = histmat[blk*NBK + b] + bstart[b];
    __syncthreads();
    const size_t e0 = (size_t)blk * EPB;
    for (int e = tid; e < EPB; e += 256) {
        unsigned d = (unsigned)getidx(ei, NE + e0 + e, i64);
        if (d >= NN) continue;
        unsigned s = (unsigned)getidx(ei, e0 + e, i64);
        float w = ld1(ew, e0 + e, f);
        if (s >= NN) { s = 0; w = 0.f; }
        int pos = atomicAdd(&cursor[d >> 7], 1);
        scr[pos] = make_int2((int)(((d & 127u) << 17) | s), __float_as_int(w));
    }
}

__global__ __launch_bounds__(256) void k_bucketdeg(
    const int* __restrict__ bstart, const int2* __restrict__ scr,
    float* __restrict__ dis) {
    __shared__ float degf[128];
    const int b = blockIdx.x, tid = threadIdx.x;
    if (tid < 128) degf[tid] = 1.0f;
    __syncthreads();
    const int r0 = bstart[b], r1 = bstart[b+1];
    for (int j = r0 + tid; j < r1; j += 256) {
        int2 m = scr[j];
        atomicAdd(&degf[(m.x >> 17) & 127], __int_as_float(m.y));
    }
    __syncthreads();
    if (tid < 128) {
        int node = b*128 + tid;
        if (node < NN) dis[node] = rsqrtf(fmaxf(degf[tid], 1e-12f));
    }
}

// per-bucket node sort: scr -> edata int2 {src, coef}; rowptr written.
// Overflow (> CAP, never here): verbatim copy + rowptr = -(b+1) sentinel.
__global__ __launch_bounds__(256) void k_sort2(
    const int* __restrict__ bstart, const float* __restrict__ dis,
    const int2* __restrict__ scr, int2* __restrict__ edata,
    int* __restrict__ rowptr) {
    __shared__ unsigned sp[CAP];
    __shared__ float    sw[CAP];
    __shared__ int cnt[128], scn[128], cur[128];
    __shared__ float disloc[128];
    const int b = blockIdx.x, tid = threadIdx.x;
    const int node0 = b * 128;
    const int r0 = bstart[b], r1 = bstart[b+1], n = r1 - r0;

    if (tid < 128) {
        int node = node0 + tid;
        disloc[tid] = (node < NN) ? dis[node] : 0.f;
        cnt[tid] = 0;
    }
    __syncthreads();
    if (n > CAP) {
        for (int j = tid; j < n; j += 256) edata[r0 + j] = scr[r0 + j];
        if (tid < 128 && node0 + tid < NN) rowptr[node0 + tid] = -(b + 1);
        return;
    }
    for (int j = tid; j < n; j += 256) {
        int2 m = scr[r0 + j];
        sp[j] = (unsigned)m.x; sw[j] = __int_as_float(m.y);
        atomicAdd(&cnt[(m.x >> 17) & 127], 1);
    }
    __syncthreads();
    if (tid < 128) scn[tid] = cnt[tid];
    __syncthreads();
    #pragma unroll
    for (int ofs = 1; ofs < 128; ofs <<= 1) {
        int a = 0;
        if (tid < 128 && tid >= ofs) a = scn[tid - ofs];
        __syncthreads();
        if (tid < 128) scn[tid] += a;
        __syncthreads();
    }
    if (tid < 128) {
        int excl = scn[tid] - cnt[tid];
        cur[tid] = excl;
        if (node0 + tid <= NN) rowptr[node0 + tid] = r0 + excl;
    }
    __syncthreads();
    for (int j = tid; j < n; j += 256) {
        unsigned p = sp[j];
        int l = (p >> 17) & 127;
        unsigned s = p & 0x1ffffu;
        int pos = atomicAdd(&cur[l], 1);
        edata[r0 + pos] = make_int2((int)s,
                                    __float_as_int(sw[j] * dis[s] * disloc[l]));
    }
}

// gather: wave per node, 2 edges per wave iter (lanes 0-31 edge j, 32-63 j+1),
// each lane handles a uint = 2 bf16 features; shfl_xor(32) merge at end.
__global__ __launch_bounds__(256) void k_gather2(
    const int* __restrict__ flag, const int* __restrict__ rowptr,
    const int* __restrict__ bstart, const int2* __restrict__ edata,
    const float* __restrict__ dis, const void* __restrict__ bias,
    const unsigned short* __restrict__ h, float* __restrict__ agg) {
    const int f = flag[0];
    const int node = blockIdx.x * 4 + (threadIdx.x >> 6);  // grid exact NN/4
    const int lane = threadIdx.x & 63;
    const int li = lane & 31, hi = lane >> 5;
    const float d2 = dis[node];
    float a0 = 0.f, a1 = 0.f;
    if (hi == 0) {
        unsigned hv = *(const unsigned*)&h[(size_t)node*64 + 2*li];
        float idg = d2 * d2;
        a0 = ld1(bias, 2*li,   f) + idg * blo(hv);
        a1 = ld1(bias, 2*li+1, f) + idg * bhi(hv);
    }
    int rp = rowptr[node];
    if (rp >= 0) {
        int l = node & 127;
        int end = (l == 127) ? bstart[(node >> 7) + 1] : rowptr[node + 1];
        int j = rp;
        for (; j + 3 < end; j += 4) {
            int2 m0 = edata[j + hi];
            int2 m1 = edata[j + 2 + hi];
            unsigned v0 = *(const unsigned*)&h[(size_t)m0.x*64 + 2*li];
            unsigned v1 = *(const unsigned*)&h[(size_t)m1.x*64 + 2*li];
            float c0 = __int_as_float(m0.y), c1 = __int_as_float(m1.y);
            a0 = fmaf(c0, blo(v0), a0); a1 = fmaf(c0, bhi(v0), a1);
            a0 = fmaf(c1, blo(v1), a0); a1 = fmaf(c1, bhi(v1), a1);
        }
        for (; j + 1 < end; j += 2) {
            int2 m0 = edata[j + hi];
            unsigned v0 = *(const unsigned*)&h[(size_t)m0.x*64 + 2*li];
            float c0 = __int_as_float(m0.y);
            a0 = fmaf(c0, blo(v0), a0); a1 = fmaf(c0, bhi(v0), a1);
        }
        if (j < end && hi == 0) {
            int2 m0 = edata[j];
            unsigned v0 = *(const unsigned*)&h[(size_t)m0.x*64 + 2*li];
            float c0 = __int_as_float(m0.y);
            a0 = fmaf(c0, blo(v0), a0); a1 = fmaf(c0, bhi(v0), a1);
        }
    } else if (hi == 0) {                 // overflow bucket (verbatim edata)
        int b = node >> 7, l = node & 127;
        for (int j2 = bstart[b]; j2 < bstart[b+1]; ++j2) {
            int2 m = edata[j2];
            if (((m.x >> 17) & 127) == l) {
                int s = m.x & 0x1ffff;
                unsigned v = *(const unsigned*)&h[(size_t)s*64 + 2*li];
                float c = __int_as_float(m.y) * dis[s] * d2;
                a0 = fmaf(c, blo(v), a0); a1 = fmaf(c, bhi(v), a1);
            }
        }
    }
    a0 += __shfl_xor(a0, 32);
    a1 += __shfl_xor(a1, 32);
    if (hi == 0)
        *(float2*)&agg[(size_t)node*64 + 2*li] = make_float2(a0, a1);
}

// ================= FALLBACK (R3) kernels =================

__global__ void k_init(float* __restrict__ dis, float* __restrict__ sums,
                       int* __restrict__ cnt) {
    int i = blockIdx.x * 256 + threadIdx.x;
    if (i < NN)  dis[i] = 1.0f;
    if (i < 384) sums[i] = 0.0f;
    if (cnt && i < NN) cnt[i] = 0;
}
__global__ void k_deg(const int* __restrict__ flag, const int* __restrict__ ei,
                      const void* __restrict__ ew, float* __restrict__ deg,
                      int* __restrict__ cnt) {
    const int f = flag[0], i64 = flag[1];
    int e = blockIdx.x * 256 + threadIdx.x;
    unsigned d = (unsigned)getidx(ei, NE + (size_t)e, i64);
    if (d < NN) {
        unsafeAtomicAdd(&deg[d], ld1(ew, e, f));
        if (cnt) atomicAdd(&cnt[d], 1);
    }
}
__global__ void k_rsqrt(float* __restrict__ dis) {
    int i = blockIdx.x * 256 + threadIdx.x;
    if (i < NN) dis[i] = rsqrtf(fmaxf(dis[i], 1e-12f));
}
__global__ void k_scan1(const int* __restrict__ cnt, int* __restrict__ rowptr,
                        int* __restrict__ blocksum) {
    __shared__ int sd[256];
    int t = threadIdx.x, i = blockIdx.x*256 + t;
    int v = (i < NN) ? cnt[i] : 0;
    sd[t] = v; __syncthreads();
    #pragma unroll
    for (int ofs = 1; ofs < 256; ofs <<= 1) {
        int a = (t >= ofs) ? sd[t-ofs] : 0;
        __syncthreads(); sd[t] += a; __syncthreads();
    }
    if (i < NN) rowptr[i] = sd[t] - v;
    if (t == 255) blocksum[blockIdx.x] = sd[255];
}
__global__ void k_scan2(int* __restrict__ blocksum) {
    __shared__ int sd[512];
    int t = threadIdx.x;
    int v = (t < 391) ? blocksum[t] : 0;
    sd[t] = v; __syncthreads();
    #pragma unroll
    for (int ofs = 1; ofs < 512; ofs <<= 1) {
        int a = (t >= ofs) ? sd[t-ofs] : 0;
        __syncthreads(); sd[t] += a; __syncthreads();
    }
    if (t < 391) blocksum[t] = sd[t] - v;
}
__global__ void k_scan3(int* __restrict__ rowptr, const int* __restrict__ blocksum,
                        int* __restrict__ cursor) {
    int i = blockIdx.x*256 + threadIdx.x;
    if (i < NN) { int r = rowptr[i] + blocksum[blockIdx.x]; rowptr[i] = r; cursor[i] = r; }
}
__global__ void k_fill(const int* __restrict__ flag, const int* __restrict__ ei,
                       const void* __restrict__ ew, const float* __restrict__ dis,
                       int* __restrict__ cursor, int* __restrict__ srcs,
                       float* __restrict__ coefs) {
    const int f = flag[0], i64 = flag[1];
    int e = blockIdx.x * 256 + threadIdx.x;
    unsigned s = (unsigned)getidx(ei, (size_t)e, i64);
    unsigned d = (unsigned)getidx(ei, NE + (size_t)e, i64);
    if (s >= NN || d >= NN) return;
    float coef = dis[s] * ld1(ew, e, f) * dis[d];
    int pos = atomicAdd(&cursor[d], 1);
    srcs[pos] = (int)s;
    coefs[pos] = coef;
}
__global__ __launch_bounds__(256) void k_gather(
    const int* __restrict__ flag, const int* __restrict__ rowptr,
    const int* __restrict__ rowend, const int* __restrict__ srcs,
    const float* __restrict__ coefs, const float* __restrict__ dis,
    const void* __restrict__ bias, const unsigned short* __restrict__ h,
    float* __restrict__ agg) {
    const int f = flag[0];
    int node = blockIdx.x * 4 + (threadIdx.x >> 6);
    int lane = threadIdx.x & 63;
    float d2 = dis[node];
    float acc = ld1(bias, lane, f) + d2*d2*bf2f(h[(size_t)node*64 + lane]);
    int j = rowptr[node], end = rowend[node];
    for (; j < end; ++j)
        acc = fmaf(coefs[j], bf2f(h[(size_t)srcs[j]*64 + lane]), acc);
    agg[(size_t)node*64 + lane] = acc;
}

// ================= dense kernels =================

__global__ __launch_bounds__(256) void k_gemm1(
    const int* __restrict__ flag, const void* __restrict__ x,
    const void* __restrict__ W, const void* __restrict__ bias,
    const float* __restrict__ dis,
    unsigned short* __restrict__ h_out, float* __restrict__ agg_out) {
    __shared__ __align__(16) float ws[128*64];
    __shared__ __align__(16) float xs[64*64];
    const int f = flag[0];
    const int tid = threadIdx.x;
    const int rowbase = blockIdx.x * 64;
    #pragma unroll
    for (int it = 0; it < 8; ++it) {
        int g = it*256 + tid;
        float4 v = ld4(W, g, f);
        int b = g*4;
        ws[b]=v.x; ws[b+1]=v.y; ws[b+2]=v.z; ws[b+3]=v.w;
    }
    const int tr = (tid >> 4) << 2;
    const int tc = (tid & 15) << 2;
    const int row = tid & 63;
    const int grow = rowbase + row;
    const bool valid = grow < NN;
    float acc[4][4] = {};
    for (int half = 0; half < 2; ++half) {
        __syncthreads();
        #pragma unroll
        for (int it = 0; it < 4; ++it) {
            int f4 = (tid >> 6) + it*4;
            int kl = f4*4;
            float4 v = make_float4(0,0,0,0);
            if (valid) v = ld4(x, (size_t)grow*32 + half*16 + f4, f);
            xs[(kl+0)*64+row]=v.x; xs[(kl+1)*64+row]=v.y;
            xs[(kl+2)*64+row]=v.z; xs[(kl+3)*64+row]=v.w;
        }
        __syncthreads();
        #pragma unroll 8
        for (int k = 0; k < 64; ++k) {
            const float4 av = *(const float4*)&xs[k*64 + tr];
            const float4 wv = *(const float4*)&ws[(half*64 + k)*64 + tc];
            const float aa[4] = {av.x, av.y, av.z, av.w};
            const float ww[4] = {wv.x, wv.y, wv.z, wv.w};
            #pragma unroll
            for (int i = 0; i < 4; ++i)
                #pragma unroll
                for (int j = 0; j < 4; ++j)
                    acc[i][j] = fmaf(aa[i], ww[j], acc[i][j]);
        }
    }
    float bc[4];
    #pragma unroll
    for (int j = 0; j < 4; ++j) bc[j] = ld1(bias, tc+j, f);
    #pragma unroll
    for (int i = 0; i < 4; ++i) {
        int r = rowbase + tr + i;
        if (r < NN) {
            ushort4 hv = make_ushort4(f2bf(acc[i][0]), f2bf(acc[i][1]),
                                      f2bf(acc[i][2]), f2bf(acc[i][3]));
            *(ushort4*)&h_out[(size_t)r*64 + tc] = hv;
            if (agg_out) {
                float dd = dis[r]; float idg = dd*dd;
                *(float4*)&agg_out[(size_t)r*64 + tc] =
                    make_float4(acc[i][0]*idg+bc[0], acc[i][1]*idg+bc[1],
                                acc[i][2]*idg+bc[2], acc[i][3]*idg+bc[3]);
            }
        }
    }
}

__global__ __launch_bounds__(256) void k_bnstats(const float* __restrict__ src,
                                                 float* __restrict__ sumout, int relu) {
    const int tid = threadIdx.x;
    float s = 0.f, q = 0.f;
    for (int i = blockIdx.x*256 + tid; i < NN*64; i += 512*256) {
        float v = src[i];
        if (relu) v = fmaxf(v, 0.f);
        s += v; q += v*v;
    }
    __shared__ float ls[256], lq[256];
    ls[tid] = s; lq[tid] = q;
    __syncthreads();
    if (tid < 64) {
        s = ls[tid]+ls[tid+64]+ls[tid+128]+ls[tid+192];
        q = lq[tid]+lq[tid+64]+lq[tid+128]+lq[tid+192];
        unsafeAtomicAdd(&sumout[tid], s);
        unsafeAtomicAdd(&sumout[64+tid], q);
    }
}

template<bool RELU, bool AGG>
__global__ __launch_bounds__(256) void k_gemm64(
    const int* __restrict__ flag, const float* __restrict__ in,
    const void* __restrict__ W, const void* __restrict__ bias,
    const void* __restrict__ g, const void* __restrict__ bb,
    const float* __restrict__ insums, const float* __restrict__ dis,
    unsigned short* __restrict__ h_out, float* __restrict__ y_out,
    float* __restrict__ outsums) {
    __shared__ __align__(16) float ws[64*64];
    __shared__ __align__(16) float xs[64*64];
    __shared__ float sc[64], sh[64];
    const int f = flag[0];
    const int tid = threadIdx.x;
    const int rowbase = blockIdx.x * 64;
    if (tid < 64) {
        float mean = insums[tid] * INV_N;
        float var  = fmaxf(insums[64+tid] * INV_N - mean*mean, 0.f);
        float s = ld1(g, tid, f) * rsqrtf(var + BN_EPS);
        sc[tid] = s;
        sh[tid] = ld1(bb, tid, f) - mean*s;
    }
    #pragma unroll
    for (int it = 0; it < 4; ++it) {
        int gi = it*256 + tid;
        float4 v = ld4(W, gi, f);
        int b = gi*4;
        ws[b]=v.x; ws[b+1]=v.y; ws[b+2]=v.z; ws[b+3]=v.w;
    }
    __syncthreads();
    {
        int row = tid & 63;
        int grow = rowbase + row;
        bool valid = grow < NN;
        #pragma unroll
        for (int it = 0; it < 4; ++it) {
            int f4 = (tid >> 6) + it*4;
            int k = f4*4;
            float4 v = make_float4(0,0,0,0);
            if (valid) v = *(const float4*)&in[(size_t)grow*64 + k];
            float a0=v.x, a1=v.y, a2=v.z, a3=v.w;
            if (RELU) { a0=fmaxf(a0,0.f); a1=fmaxf(a1,0.f); a2=fmaxf(a2,0.f); a3=fmaxf(a3,0.f); }
            a0 = a0*sc[k+0]+sh[k+0]; a1 = a1*sc[k+1]+sh[k+1];
            a2 = a2*sc[k+2]+sh[k+2]; a3 = a3*sc[k+3]+sh[k+3];
            xs[(k+0)*64+row]=a0; xs[(k+1)*64+row]=a1;
            xs[(k+2)*64+row]=a2; xs[(k+3)*64+row]=a3;
        }
    }
    __syncthreads();
    const int tr = (tid >> 4) << 2;
    const int tc = (tid & 15) << 2;
    float acc[4][4] = {};
    #pragma unroll 8
    for (int k = 0; k < 64; ++k) {
        const float4 av = *(const float4*)&xs[k*64 + tr];
        const float4 wv = *(const float4*)&ws[k*64 + tc];
        const float aa[4] = {av.x, av.y, av.z, av.w};
        const float ww[4] = {wv.x, wv.y, wv.z, wv.w};
        #pragma unroll
        for (int i = 0; i < 4; ++i)
            #pragma unroll
            for (int j = 0; j < 4; ++j)
                acc[i][j] = fmaf(aa[i], ww[j], acc[i][j]);
    }
    float bc[4];
    #pragma unroll
    for (int j = 0; j < 4; ++j) bc[j] = ld1(bias, tc+j, f);
    if (AGG) {
        #pragma unroll
        for (int i = 0; i < 4; ++i) {
            int r = rowbase + tr + i;
            if (r < NN) {
                ushort4 hv = make_ushort4(f2bf(acc[i][0]), f2bf(acc[i][1]),
                                          f2bf(acc[i][2]), f2bf(acc[i][3]));
                *(ushort4*)&h_out[(size_t)r*64 + tc] = hv;
                if (y_out) {
                    float dd = dis[r]; float idg = dd*dd;
                    *(float4*)&y_out[(size_t)r*64 + tc] =
                        make_float4(acc[i][0]*idg+bc[0], acc[i][1]*idg+bc[1],
                                    acc[i][2]*idg+bc[2], acc[i][3]*idg+bc[3]);
                }
            }
        }
    } else {
        float ps[4] = {0,0,0,0}, pq[4] = {0,0,0,0};
        #pragma unroll
        for (int i = 0; i < 4; ++i) {
            int r = rowbase + tr + i;
            if (r < NN) {
                float y0 = acc[i][0]+bc[0], y1 = acc[i][1]+bc[1];
                float y2 = acc[i][2]+bc[2], y3 = acc[i][3]+bc[3];
                *(float4*)&y_out[(size_t)r*64 + tc] = make_float4(y0,y1,y2,y3);
                ps[0]+=y0; ps[1]+=y1; ps[2]+=y2; ps[3]+=y3;
                pq[0]+=y0*y0; pq[1]+=y1*y1; pq[2]+=y2*y2; pq[3]+=y3*y3;
            }
        }
        __syncthreads();
        int grp = tid >> 4;
        #pragma unroll
        for (int j = 0; j < 4; ++j) { xs[grp*64 + tc+j] = ps[j]; ws[grp*64 + tc+j] = pq[j]; }
        __syncthreads();
        if (tid < 64) {
            float s = 0.f, q = 0.f;
            #pragma unroll
            for (int g2 = 0; g2 < 16; ++g2) { s += xs[g2*64+tid]; q += ws[g2*64+tid]; }
            unsafeAtomicAdd(&outsums[tid], s);
            unsafeAtomicAdd(&outsums[64+tid], q);
        }
    }
}

__global__ __launch_bounds__(256) void k_final(
    const int* __restrict__ flag, const float* __restrict__ y3,
    const void* __restrict__ g, const void* __restrict__ bb,
    const float* __restrict__ sums, const void* __restrict__ w2,
    const void* __restrict__ b2, void* __restrict__ out) {
    __shared__ __align__(16) float tile[64*64];
    __shared__ float wp[64], tv[64];
    const int f = flag[0];
    const int tid = threadIdx.x;
    const int base = blockIdx.x * 64;
    if (tid < 64) {
        float mean = sums[tid] * INV_N;
        float var  = fmaxf(sums[64+tid] * INV_N - mean*mean, 0.f);
        float s = ld1(g, tid, f) * rsqrtf(var + BN_EPS);
        float t = ld1(bb, tid, f) - mean*s;
        float w = ld1(w2, tid, f);
        wp[tid] = s*w; tv[tid] = t*w;
    }
    #pragma unroll
    for (int it = 0; it < 4; ++it) {
        int i4 = it*256 + tid;
        int row = i4 >> 4;
        float4 v = make_float4(0,0,0,0);
        if (base + row < NN) v = *(const float4*)&y3[(size_t)base*64 + i4*4];
        *(float4*)&tile[i4*4] = v;
    }
    __syncthreads();
    if (tid < 64 && base + tid < NN) {
        float a = ld1(b2, 0, f);
        #pragma unroll
        for (int c = 0; c < 64; ++c) a += tv[c];
        #pragma unroll
        for (int cc = 0; cc < 64; ++cc) {
            int c = (cc + tid) & 63;
            a += tile[tid*64 + c] * wp[c];
        }
        if (f) ((float*)out)[base + tid] = a;
        else   ((unsigned short*)out)[base + tid] = f2bf(a);
    }
}

extern "C" void kernel_launch(void* const* d_in, const int* in_sizes, int n_in,
                              void* d_out, int out_size, void* d_ws, size_t ws_size,
                              hipStream_t stream) {
    const unsigned short* x = (const unsigned short*)d_in[0];
    const void* ew  = d_in[1];
    const void* W1  = d_in[2];
    const void* b1  = d_in[3];
    const void* W2  = d_in[4];
    const void* b2  = d_in[5];
    const void* l1W = d_in[6];
    const void* l1b = d_in[7];
    const void* l2W = d_in[8];
    const void* l2b = d_in[9];
    const void* g1  = d_in[10];
    const void* bb1 = d_in[11];
    const void* g2  = d_in[12];
    const void* bb2 = d_in[13];
    const void* g3  = d_in[14];
    const void* bb3 = d_in[15];
    const int* eidx = (const int*)d_in[16];

    // common layout (float idx): flag 0, sums 16, dis 400, agg 100400..6500400,
    // hbuf(ushort) 6500400..9700400
    int*   flag = (int*)d_ws;
    float* wsf  = (float*)d_ws;
    float* sums = wsf + 16;
    float* dis  = wsf + 400;
    float* agg  = wsf + 100400;
    unsigned short* hbuf = (unsigned short*)(wsf + 6500400);

    // fast-path overlay (== R4/R5's proven 66,011,328 B):
    // histmat/rowptr 9700400 (400,384 ints), btot 10100784, bstart 10101808,
    // edata(int2) 10102832 (6.4M ints). Unsorted scratch scr(int2) lives in
    // the agg region (3.2M int2 == 6.4M floats) until gather overwrites it.
    int*  histmat = (int*)(wsf + 9700400);
    int*  rowptr2 = histmat;
    int*  btot    = (int*)(wsf + 10100784);
    int*  bstart  = (int*)(wsf + 10101808);
    int2* edata   = (int2*)(wsf + 10102832);
    int2* scr     = (int2*)(wsf + 100400);
    const size_t NEED_NEW = (size_t)16502832 * 4;

    // R3 fallback overlay
    int*   rowptr   = (int*)(wsf + 9700400);
    int*   cursor   = (int*)(wsf + 9800400);
    int*   blocksum = (int*)(wsf + 9900400);
    int*   srcs     = (int*)(wsf + 9900912);
    float* coefs    = wsf + 13100912;
    const size_t NEED_CSR = (size_t)16300912 * 4;

    if (ws_size < NEED_CSR) return;
    const bool fast = ws_size >= NEED_NEW;

    if (fast) {
        k_detect2  <<<1, 256, 0, stream>>>(x, eidx, flag, sums);
        k_hist     <<<NSB, 256, 0, stream>>>(flag, eidx, histmat);
        k_scanA    <<<NBK, 256, 0, stream>>>(histmat, btot);
        k_scanB    <<<1, 1024, 0, stream>>>(btot, bstart);
        k_scatter  <<<NSB, 256, 0, stream>>>(flag, eidx, ew, histmat, bstart, scr);
        k_bucketdeg<<<NBK, 256, 0, stream>>>(bstart, scr, dis);
        k_sort2    <<<NBK, 256, 0, stream>>>(bstart, dis, scr, edata, rowptr2);
        // layer 1
        k_gemm1    <<<1563, 256, 0, stream>>>(flag, x, W1, b1, dis, hbuf, nullptr);
        k_gather2  <<<NN/4, 256, 0, stream>>>(flag, rowptr2, bstart, edata,
                                              dis, b1, hbuf, agg);
        k_bnstats  <<<512, 256, 0, stream>>>(agg, sums + 0, 1);
        // layer 2
        k_gemm64<true, true><<<1563, 256, 0, stream>>>(flag, agg, W2, b2, g1, bb1,
                                                       sums + 0, dis, hbuf, nullptr, nullptr);
        k_gather2  <<<NN/4, 256, 0, stream>>>(flag, rowptr2, bstart, edata,
                                              dis, b2, hbuf, agg);
    } else {
        k_detect2<<<1, 256, 0, stream>>>(x, eidx, flag, sums);
        k_init  <<<391, 256, 0, stream>>>(dis, sums, cursor);
        k_deg   <<<NE/256, 256, 0, stream>>>(flag, eidx, ew, dis, cursor);
        k_rsqrt <<<391, 256, 0, stream>>>(dis);
        k_scan1 <<<391, 256, 0, stream>>>(cursor, rowptr, blocksum);
        k_scan2 <<<1, 512, 0, stream>>>(blocksum);
        k_scan3 <<<391, 256, 0, stream>>>(rowptr, blocksum, cursor);
        k_fill  <<<NE/256, 256, 0, stream>>>(flag, eidx, ew, dis, cursor, srcs, coefs);
        k_gemm1 <<<1563, 256, 0, stream>>>(flag, x, W1, b1, dis, hbuf, nullptr);
        k_gather<<<NN/4, 256, 0, stream>>>(flag, rowptr, cursor, srcs, coefs,
                                           dis, b1, hbuf, agg);
        k_bnstats<<<512, 256, 0, stream>>>(agg, sums + 0, 1);
        k_gemm64<true, true><<<1563, 256, 0, stream>>>(flag, agg, W2, b2, g1, bb1,
                                                       sums + 0, dis, hbuf, nullptr, nullptr);
        k_gather<<<NN/4, 256, 0, stream>>>(flag, rowptr, cursor, srcs, coefs,
                                           dis, b2, hbuf, agg);
    }
    k_bnstats<<<512, 256, 0, stream>>>(agg, sums + 128, 0);
    k_gemm64<false, false><<<1563, 256, 0, stream>>>(flag, agg, l1W, l1b, g2, bb2,
                                                     sums + 128, dis, hbuf, agg, sums + 256);
    k_final <<<1563, 256, 0, stream>>>(flag, agg, g3, bb3, sums + 256, l2W, l2b, d_out);
}

// Round 7
// 632.101 us; speedup vs baseline: 5.0529x; 1.1029x over previous
//
#include <hip/hip_runtime.h>
#include <hip/hip_bf16.h>

// R7: (1) bucketdeg fused into sort (k_sortdeg): edata = {src, w}; gather
// computes coef = w*dis[s]*dis[d] on the fly -> one fewer kernel + one fewer
// 25.6 MB pass. Overflow buckets handled by a correct two-stream path (no
// sentinel in gather). (2) gather unrolled to 8 edges/iter for memory-level
// parallelism (gather was fetch-latency bound: VALUBusy 30%, FETCH 308MB).
// (3) bnstats vectorized float4. ws layout/need unchanged (proven 66 MB).

#define NN 100000
#define NE 3200000
#define INV_N (1.0f/100000.0f)
#define BN_EPS 1e-5f
#define NBK 782            // buckets of 128 nodes
#define NSB 512            // scatter/hist blocks
#define EPB 6250           // edges per scatter/hist block (NSB*EPB == NE)
#define CAP 7424           // LDS staging capacity per bucket (mean 4092, 52 sigma)

static __device__ __forceinline__ float bf2f(unsigned short u) {
    if ((u & 0x7f80u) == 0x7f80u) u = 0;          // inf/NaN -> 0 (input scrub)
    union { unsigned int i; float f; } z; z.i = ((unsigned int)u) << 16; return z.f;
}
static __device__ __forceinline__ float scrubf(float v) {
    return (fabsf(v) < 1e30f) ? v : 0.f;
}
static __device__ __forceinline__ unsigned short f2bf(float v) {
    union { float f; unsigned int i; } z; z.f = v;
    unsigned int lsb = (z.i >> 16) & 1u; z.i += 0x7fffu + lsb;
    return (unsigned short)(z.i >> 16);
}
static __device__ __forceinline__ float ld1(const void* p, size_t i, int f) {
    return f ? scrubf(((const float*)p)[i]) : bf2f(((const unsigned short*)p)[i]);
}
static __device__ __forceinline__ float4 ld4(const void* p, size_t g, int f) {
    if (f) { float4 v = ((const float4*)p)[g];
             return make_float4(scrubf(v.x),scrubf(v.y),scrubf(v.z),scrubf(v.w)); }
    ushort4 u = ((const ushort4*)p)[g];
    return make_float4(bf2f(u.x),bf2f(u.y),bf2f(u.z),bf2f(u.w));
}
static __device__ __forceinline__ int getidx(const int* ei, size_t pos, int i64) {
    return i64 ? ei[2*pos] : ei[pos];
}
static __device__ __forceinline__ float blo(unsigned v) {
    union { unsigned u; float f; } z; z.u = v << 16; return z.f;
}
static __device__ __forceinline__ float bhi(unsigned v) {
    union { unsigned u; float f; } z; z.u = v & 0xffff0000u; return z.f;
}

// ---------------- detector + sums zero ----------------
__global__ void k_detect2(const unsigned short* __restrict__ x,
                          const int* __restrict__ ei, int* __restrict__ flag,
                          float* __restrict__ sums) {
    __shared__ int cnt[256];
    int tid = threadIdx.x, c = 0;
    for (int i = tid; i < 1024; i += 256) {
        unsigned short u = x[i];
        int ex = (u >> 7) & 0xff;
        if ((u & 0x7fffu) != 0 && (ex >= 0xB0 || ex <= 0x40)) c++;
    }
    cnt[tid] = c; __syncthreads();
    if (tid == 0) { int t = 0; for (int i = 0; i < 256; ++i) t += cnt[i];
                    flag[0] = (t > 64) ? 1 : 0; }
    if (tid == 1) { int nz = 0; for (int i = 1; i < 64; i += 2) nz |= ei[i];
                    flag[1] = (nz == 0) ? 1 : 0; }
    if (tid < 128) { sums[tid]=0.f; sums[128+tid]=0.f; sums[256+tid]=0.f; }
}

// ================= bucket counting sort (no global atomics) =================

__global__ __launch_bounds__(256) void k_hist(const int* __restrict__ flag,
                                              const int* __restrict__ ei,
                                              int* __restrict__ histmat) {
    __shared__ int hh[NBK];
    const int i64 = flag[1];
    const int blk = blockIdx.x, tid = threadIdx.x;
    for (int b = tid; b < NBK; b += 256) hh[b] = 0;
    __syncthreads();
    const size_t e0 = (size_t)blk * EPB;
    for (int e = tid; e < EPB; e += 256) {
        unsigned d = (unsigned)getidx(ei, NE + e0 + e, i64);
        if (d < NN) atomicAdd(&hh[d >> 7], 1);
    }
    __syncthreads();
    for (int b = tid; b < NBK; b += 256) histmat[blk*NBK + b] = hh[b];
}

__global__ __launch_bounds__(256) void k_scanA(int* __restrict__ histmat,
                                               int* __restrict__ btot) {
    __shared__ int sd[256];
    const int b = blockIdx.x, t = threadIdx.x;
    int v0 = histmat[(2*t)*NBK + b];
    int v1 = histmat[(2*t+1)*NBK + b];
    int ts = v0 + v1;
    sd[t] = ts; __syncthreads();
    #pragma unroll
    for (int ofs = 1; ofs < 256; ofs <<= 1) {
        int a = (t >= ofs) ? sd[t-ofs] : 0;
        __syncthreads(); sd[t] += a; __syncthreads();
    }
    int excl = sd[t] - ts;
    histmat[(2*t)*NBK + b]   = excl;
    histmat[(2*t+1)*NBK + b] = excl + v0;
    if (t == 255) btot[b] = sd[255];
}

__global__ void k_scanB(const int* __restrict__ btot, int* __restrict__ bstart) {
    __shared__ int sd[1024];
    int t = threadIdx.x;                 // 1024 threads
    int v = (t < NBK) ? btot[t] : 0;
    sd[t] = v; __syncthreads();
    #pragma unroll
    for (int ofs = 1; ofs < 1024; ofs <<= 1) {
        int a = (t >= ofs) ? sd[t-ofs] : 0;
        __syncthreads(); sd[t] += a; __syncthreads();
    }
    if (t <= NBK) bstart[t] = sd[t] - v;   // bstart[NBK] = total
}

// scatter edges -> scratch (bucket-grouped int2 {dloc<<17|src, w}); LDS atomics only
__global__ __launch_bounds__(256) void k_scatter(
    const int* __restrict__ flag, const int* __restrict__ ei,
    const void* __restrict__ ew, const int* __restrict__ histmat,
    const int* __restrict__ bstart, int2* __restrict__ scr) {
    __shared__ int cursor[NBK];
    const int f = flag[0], i64 = flag[1];
    const int blk = blockIdx.x, tid = threadIdx.x;
    for (int b = tid; b < NBK; b += 256)
        cursor[b] = histmat[blk*NBK + b] + bstart[b];
    __syncthreads();
    const size_t e0 = (size_t)blk * EPB;
    for (int e = tid; e < EPB; e += 256) {
        unsigned d = (unsigned)getidx(ei, NE + e0 + e, i64);
        if (d >= NN) continue;
        unsigned s = (unsigned)getidx(ei, e0 + e, i64);
        float w = ld1(ew, e0 + e, f);
        if (s >= NN) { s = 0; w = 0.f; }
        int pos = atomicAdd(&cursor[d >> 7], 1);
        scr[pos] = make_int2((int)(((d & 127u) << 17) | s), __float_as_int(w));
    }
}

// fused per-bucket node-sort + degree: scr -> edata {src, w}; writes rowptr, dis.
// n <= CAP: LDS-staged single global read. n > CAP: correct two-stream path.
__global__ __launch_bounds__(256) void k_sortdeg(
    const int* __restrict__ bstart, const int2* __restrict__ scr,
    int2* __restrict__ edata, int* __restrict__ rowptr, float* __restrict__ dis) {
    __shared__ unsigned sp[CAP];
    __shared__ float    sw[CAP];
    __shared__ int cnt[128], scn[128], cur[128];
    __shared__ float degf[128];
    const int b = blockIdx.x, tid = threadIdx.x;
    const int node0 = b * 128;
    const int r0 = bstart[b], r1 = bstart[b+1], n = r1 - r0;
    const bool fit = (n <= CAP);

    if (tid < 128) { cnt[tid] = 0; degf[tid] = 1.0f; }
    __syncthreads();
    if (fit) {
        for (int j = tid; j < n; j += 256) {
            int2 m = scr[r0 + j];
            sp[j] = (unsigned)m.x; sw[j] = __int_as_float(m.y);
            int l = (m.x >> 17) & 127;
            atomicAdd(&cnt[l], 1);
            atomicAdd(&degf[l], __int_as_float(m.y));
        }
    } else {
        for (int j = tid; j < n; j += 256) {
            int2 m = scr[r0 + j];
            int l = (m.x >> 17) & 127;
            atomicAdd(&cnt[l], 1);
            atomicAdd(&degf[l], __int_as_float(m.y));
        }
    }
    __syncthreads();
    if (tid < 128) scn[tid] = cnt[tid];
    __syncthreads();
    #pragma unroll
    for (int ofs = 1; ofs < 128; ofs <<= 1) {
        int a = 0;
        if (tid < 128 && tid >= ofs) a = scn[tid - ofs];
        __syncthreads();
        if (tid < 128) scn[tid] += a;
        __syncthreads();
    }
    if (tid < 128) {
        int excl = scn[tid] - cnt[tid];
        cur[tid] = excl;
        int node = node0 + tid;
        if (node <= NN) rowptr[node] = r0 + excl;
        if (node <  NN) dis[node] = rsqrtf(fmaxf(degf[tid], 1e-12f));
    }
    __syncthreads();
    if (fit) {
        for (int j = tid; j < n; j += 256) {
            unsigned p = sp[j];
            int l = (p >> 17) & 127;
            int pos = atomicAdd(&cur[l], 1);
            edata[r0 + pos] = make_int2((int)(p & 0x1ffffu), __float_as_int(sw[j]));
        }
    } else {
        for (int j = tid; j < n; j += 256) {
            int2 m = scr[r0 + j];
            int l = (m.x >> 17) & 127;
            int pos = atomicAdd(&cur[l], 1);
            edata[r0 + pos] = make_int2(m.x & 0x1ffff, m.y);
        }
    }
}

// gather: wave per node; 8 edges in flight per iteration (4 per half-wave);
// lanes 0-31 even edges, 32-63 odd; uint load = 2 bf16 features;
// coef = w * dis[src] * dis[dst] computed on the fly; shfl_xor(32) merge.
__global__ __launch_bounds__(256) void k_gather3(
    const int* __restrict__ flag, const int* __restrict__ rowptr,
    const int* __restrict__ bstart, const int2* __restrict__ edata,
    const float* __restrict__ dis, const void* __restrict__ bias,
    const unsigned short* __restrict__ h, float* __restrict__ agg) {
    const int f = flag[0];
    const int node = blockIdx.x * 4 + (threadIdx.x >> 6);  // grid exact NN/4
    const int lane = threadIdx.x & 63;
    const int li = lane & 31, hi = lane >> 5;
    const float d2 = dis[node];
    const unsigned* h32 = (const unsigned*)h;
    float a0 = 0.f, a1 = 0.f;
    if (hi == 0) {
        unsigned hv = h32[(size_t)node*32 + li];
        float idg = d2 * d2;
        a0 = ld1(bias, 2*li,   f) + idg * blo(hv);
        a1 = ld1(bias, 2*li+1, f) + idg * bhi(hv);
    }
    int j = rowptr[node];
    const int l = node & 127;
    const int end = (l == 127) ? bstart[(node >> 7) + 1] : rowptr[node + 1];
    for (; j + 7 < end; j += 8) {
        int2 m0 = edata[j +     hi];
        int2 m1 = edata[j + 2 + hi];
        int2 m2 = edata[j + 4 + hi];
        int2 m3 = edata[j + 6 + hi];
        unsigned v0 = h32[(size_t)m0.x*32 + li];
        unsigned v1 = h32[(size_t)m1.x*32 + li];
        unsigned v2 = h32[(size_t)m2.x*32 + li];
        unsigned v3 = h32[(size_t)m3.x*32 + li];
        float c0 = __int_as_float(m0.y) * dis[m0.x] * d2;
        float c1 = __int_as_float(m1.y) * dis[m1.x] * d2;
        float c2 = __int_as_float(m2.y) * dis[m2.x] * d2;
        float c3 = __int_as_float(m3.y) * dis[m3.x] * d2;
        a0 = fmaf(c0, blo(v0), a0); a1 = fmaf(c0, bhi(v0), a1);
        a0 = fmaf(c1, blo(v1), a0); a1 = fmaf(c1, bhi(v1), a1);
        a0 = fmaf(c2, blo(v2), a0); a1 = fmaf(c2, bhi(v2), a1);
        a0 = fmaf(c3, blo(v3), a0); a1 = fmaf(c3, bhi(v3), a1);
    }
    for (; j + 1 < end; j += 2) {
        int2 m0 = edata[j + hi];
        unsigned v0 = h32[(size_t)m0.x*32 + li];
        float c0 = __int_as_float(m0.y) * dis[m0.x] * d2;
        a0 = fmaf(c0, blo(v0), a0); a1 = fmaf(c0, bhi(v0), a1);
    }
    if (j < end && hi == 0) {
        int2 m0 = edata[j];
        unsigned v0 = h32[(size_t)m0.x*32 + li];
        float c0 = __int_as_float(m0.y) * dis[m0.x] * d2;
        a0 = fmaf(c0, blo(v0), a0); a1 = fmaf(c0, bhi(v0), a1);
    }
    a0 += __shfl_xor(a0, 32);
    a1 += __shfl_xor(a1, 32);
    if (hi == 0)
        *(float2*)&agg[(size_t)node*64 + 2*li] = make_float2(a0, a1);
}

// ================= FALLBACK (R3) kernels =================

__global__ void k_init(float* __restrict__ dis, float* __restrict__ sums,
                       int* __restrict__ cnt) {
    int i = blockIdx.x * 256 + threadIdx.x;
    if (i < NN)  dis[i] = 1.0f;
    if (i < 384) sums[i] = 0.0f;
    if (cnt && i < NN) cnt[i] = 0;
}
__global__ void k_deg(const int* __restrict__ flag, const int* __restrict__ ei,
                      const void* __restrict__ ew, float* __restrict__ deg,
                      int* __restrict__ cnt) {
    const int f = flag[0], i64 = flag[1];
    int e = blockIdx.x * 256 + threadIdx.x;
    unsigned d = (unsigned)getidx(ei, NE + (size_t)e, i64);
    if (d < NN) {
        unsafeAtomicAdd(&deg[d], ld1(ew, e, f));
        if (cnt) atomicAdd(&cnt[d], 1);
    }
}
__global__ void k_rsqrt(float* __restrict__ dis) {
    int i = blockIdx.x * 256 + threadIdx.x;
    if (i < NN) dis[i] = rsqrtf(fmaxf(dis[i], 1e-12f));
}
__global__ void k_scan1(const int* __restrict__ cnt, int* __restrict__ rowptr,
                        int* __restrict__ blocksum) {
    __shared__ int sd[256];
    int t = threadIdx.x, i = blockIdx.x*256 + t;
    int v = (i < NN) ? cnt[i] : 0;
    sd[t] = v; __syncthreads();
    #pragma unroll
    for (int ofs = 1; ofs < 256; ofs <<= 1) {
        int a = (t >= ofs) ? sd[t-ofs] : 0;
        __syncthreads(); sd[t] += a; __syncthreads();
    }
    if (i < NN) rowptr[i] = sd[t] - v;
    if (t == 255) blocksum[blockIdx.x] = sd[255];
}
__global__ void k_scan2(int* __restrict__ blocksum) {
    __shared__ int sd[512];
    int t = threadIdx.x;
    int v = (t < 391) ? blocksum[t] : 0;
    sd[t] = v; __syncthreads();
    #pragma unroll
    for (int ofs = 1; ofs < 512; ofs <<= 1) {
        int a = (t >= ofs) ? sd[t-ofs] : 0;
        __syncthreads(); sd[t] += a; __syncthreads();
    }
    if (t < 391) blocksum[t] = sd[t] - v;
}
__global__ void k_scan3(int* __restrict__ rowptr, const int* __restrict__ blocksum,
                        int* __restrict__ cursor) {
    int i = blockIdx.x*256 + threadIdx.x;
    if (i < NN) { int r = rowptr[i] + blocksum[blockIdx.x]; rowptr[i] = r; cursor[i] = r; }
}
__global__ void k_fill(const int* __restrict__ flag, const int* __restrict__ ei,
                       const void* __restrict__ ew, const float* __restrict__ dis,
                       int* __restrict__ cursor, int* __restrict__ srcs,
                       float* __restrict__ coefs) {
    const int f = flag[0], i64 = flag[1];
    int e = blockIdx.x * 256 + threadIdx.x;
    unsigned s = (unsigned)getidx(ei, (size_t)e, i64);
    unsigned d = (unsigned)getidx(ei, NE + (size_t)e, i64);
    if (s >= NN || d >= NN) return;
    float coef = dis[s] * ld1(ew, e, f) * dis[d];
    int pos = atomicAdd(&cursor[d], 1);
    srcs[pos] = (int)s;
    coefs[pos] = coef;
}
__global__ __launch_bounds__(256) void k_gather(
    const int* __restrict__ flag, const int* __restrict__ rowptr,
    const int* __restrict__ rowend, const int* __restrict__ srcs,
    const float* __restrict__ coefs, const float* __restrict__ dis,
    const void* __restrict__ bias, const unsigned short* __restrict__ h,
    float* __restrict__ agg) {
    const int f = flag[0];
    int node = blockIdx.x * 4 + (threadIdx.x >> 6);
    int lane = threadIdx.x & 63;
    float d2 = dis[node];
    float acc = ld1(bias, lane, f) + d2*d2*bf2f(h[(size_t)node*64 + lane]);
    int j = rowptr[node], end = rowend[node];
    for (; j < end; ++j)
        acc = fmaf(coefs[j], bf2f(h[(size_t)srcs[j]*64 + lane]), acc);
    agg[(size_t)node*64 + lane] = acc;
}

// ================= dense kernels =================

__global__ __launch_bounds__(256) void k_gemm1(
    const int* __restrict__ flag, const void* __restrict__ x,
    const void* __restrict__ W, const void* __restrict__ bias,
    const float* __restrict__ dis,
    unsigned short* __restrict__ h_out, float* __restrict__ agg_out) {
    __shared__ __align__(16) float ws[128*64];
    __shared__ __align__(16) float xs[64*64];
    const int f = flag[0];
    const int tid = threadIdx.x;
    const int rowbase = blockIdx.x * 64;
    #pragma unroll
    for (int it = 0; it < 8; ++it) {
        int g = it*256 + tid;
        float4 v = ld4(W, g, f);
        int b = g*4;
        ws[b]=v.x; ws[b+1]=v.y; ws[b+2]=v.z; ws[b+3]=v.w;
    }
    const int tr = (tid >> 4) << 2;
    const int tc = (tid & 15) << 2;
    const int row = tid & 63;
    const int grow = rowbase + row;
    const bool valid = grow < NN;
    float acc[4][4] = {};
    for (int half = 0; half < 2; ++half) {
        __syncthreads();
        #pragma unroll
        for (int it = 0; it < 4; ++it) {
            int f4 = (tid >> 6) + it*4;
            int kl = f4*4;
            float4 v = make_float4(0,0,0,0);
            if (valid) v = ld4(x, (size_t)grow*32 + half*16 + f4, f);
            xs[(kl+0)*64+row]=v.x; xs[(kl+1)*64+row]=v.y;
            xs[(kl+2)*64+row]=v.z; xs[(kl+3)*64+row]=v.w;
        }
        __syncthreads();
        #pragma unroll 8
        for (int k = 0; k < 64; ++k) {
            const float4 av = *(const float4*)&xs[k*64 + tr];
            const float4 wv = *(const float4*)&ws[(half*64 + k)*64 + tc];
            const float aa[4] = {av.x, av.y, av.z, av.w};
            const float ww[4] = {wv.x, wv.y, wv.z, wv.w};
            #pragma unroll
            for (int i = 0; i < 4; ++i)
                #pragma unroll
                for (int j = 0; j < 4; ++j)
                    acc[i][j] = fmaf(aa[i], ww[j], acc[i][j]);
        }
    }
    float bc[4];
    #pragma unroll
    for (int j = 0; j < 4; ++j) bc[j] = ld1(bias, tc+j, f);
    #pragma unroll
    for (int i = 0; i < 4; ++i) {
        int r = rowbase + tr + i;
        if (r < NN) {
            ushort4 hv = make_ushort4(f2bf(acc[i][0]), f2bf(acc[i][1]),
                                      f2bf(acc[i][2]), f2bf(acc[i][3]));
            *(ushort4*)&h_out[(size_t)r*64 + tc] = hv;
            if (agg_out) {
                float dd = dis[r]; float idg = dd*dd;
                *(float4*)&agg_out[(size_t)r*64 + tc] =
                    make_float4(acc[i][0]*idg+bc[0], acc[i][1]*idg+bc[1],
                                acc[i][2]*idg+bc[2], acc[i][3]*idg+bc[3]);
            }
        }
    }
}

// float4 BN column stats (optionally after relu); 512 blocks
__global__ __launch_bounds__(256) void k_bnstats4(const float4* __restrict__ src,
                                                  float* __restrict__ sumout, int relu) {
    const int tid = threadIdx.x;
    float s0=0,s1=0,s2=0,s3=0, q0=0,q1=0,q2=0,q3=0;
    for (int g = blockIdx.x*256 + tid; g < NN*16; g += 512*256) {
        float4 v = src[g];
        if (relu) { v.x=fmaxf(v.x,0.f); v.y=fmaxf(v.y,0.f);
                    v.z=fmaxf(v.z,0.f); v.w=fmaxf(v.w,0.f); }
        s0+=v.x; q0+=v.x*v.x; s1+=v.y; q1+=v.y*v.y;
        s2+=v.z; q2+=v.z*v.z; s3+=v.w; q3+=v.w*v.w;
    }
    __shared__ float ls[1024], lq[1024];
    ls[tid*4+0]=s0; ls[tid*4+1]=s1; ls[tid*4+2]=s2; ls[tid*4+3]=s3;
    lq[tid*4+0]=q0; lq[tid*4+1]=q1; lq[tid*4+2]=q2; lq[tid*4+3]=q3;
    __syncthreads();
    // feature fx contributions: threads t with (t&15)==fx>>2, component fx&3
    if (tid < 64) {
        int grp = tid >> 2, k = tid & 3;
        float s = 0.f, q = 0.f;
        #pragma unroll
        for (int m = 0; m < 16; ++m) {
            int idx = (grp + 16*m)*4 + k;
            s += ls[idx]; q += lq[idx];
        }
        unsafeAtomicAdd(&sumout[tid], s);
        unsafeAtomicAdd(&sumout[64+tid], q);
    }
}

template<bool RELU, bool AGG>
__global__ __launch_bounds__(256) void k_gemm64(
    const int* __restrict__ flag, const float* __restrict__ in,
    const void* __restrict__ W, const void* __restrict__ bias,
    const void* __restrict__ g, const void* __restrict__ bb,
    const float* __restrict__ insums, const float* __restrict__ dis,
    unsigned short* __restrict__ h_out, float* __restrict__ y_out,
    float* __restrict__ outsums) {
    __shared__ __align__(16) float ws[64*64];
    __shared__ __align__(16) float xs[64*64];
    __shared__ float sc[64], sh[64];
    const int f = flag[0];
    const int tid = threadIdx.x;
    const int rowbase = blockIdx.x * 64;
    if (tid < 64) {
        float mean = insums[tid] * INV_N;
        float var  = fmaxf(insums[64+tid] * INV_N - mean*mean, 0.f);
        float s = ld1(g, tid, f) * rsqrtf(var + BN_EPS);
        sc[tid] = s;
        sh[tid] = ld1(bb, tid, f) - mean*s;
    }
    #pragma unroll
    for (int it = 0; it < 4; ++it) {
        int gi = it*256 + tid;
        float4 v = ld4(W, gi, f);
        int b = gi*4;
        ws[b]=v.x; ws[b+1]=v.y; ws[b+2]=v.z; ws[b+3]=v.w;
    }
    __syncthreads();
    {
        int row = tid & 63;
        int grow = rowbase + row;
        bool valid = grow < NN;
        #pragma unroll
        for (int it = 0; it < 4; ++it) {
            int f4 = (tid >> 6) + it*4;
            int k = f4*4;
            float4 v = make_float4(0,0,0,0);
            if (valid) v = *(const float4*)&in[(size_t)grow*64 + k];
            float a0=v.x, a1=v.y, a2=v.z, a3=v.w;
            if (RELU) { a0=fmaxf(a0,0.f); a1=fmaxf(a1,0.f); a2=fmaxf(a2,0.f); a3=fmaxf(a3,0.f); }
            a0 = a0*sc[k+0]+sh[k+0]; a1 = a1*sc[k+1]+sh[k+1];
            a2 = a2*sc[k+2]+sh[k+2]; a3 = a3*sc[k+3]+sh[k+3];
            xs[(k+0)*64+row]=a0; xs[(k+1)*64+row]=a1;
            xs[(k+2)*64+row]=a2; xs[(k+3)*64+row]=a3;
        }
    }
    __syncthreads();
    const int tr = (tid >> 4) << 2;
    const int tc = (tid & 15) << 2;
    float acc[4][4] = {};
    #pragma unroll 8
    for (int k = 0; k < 64; ++k) {
        const float4 av = *(const float4*)&xs[k*64 + tr];
        const float4 wv = *(const float4*)&ws[k*64 + tc];
        const float aa[4] = {av.x, av.y, av.z, av.w};
        const float ww[4] = {wv.x, wv.y, wv.z, wv.w};
        #pragma unroll
        for (int i = 0; i < 4; ++i)
            #pragma unroll
            for (int j = 0; j < 4; ++j)
                acc[i][j] = fmaf(aa[i], ww[j], acc[i][j]);
    }
    float bc[4];
    #pragma unroll
    for (int j = 0; j < 4; ++j) bc[j] = ld1(bias, tc+j, f);
    if (AGG) {
        #pragma unroll
        for (int i = 0; i < 4; ++i) {
            int r = rowbase + tr + i;
            if (r < NN) {
                ushort4 hv = make_ushort4(f2bf(acc[i][0]), f2bf(acc[i][1]),
                                          f2bf(acc[i][2]), f2bf(acc[i][3]));
                *(ushort4*)&h_out[(size_t)r*64 + tc] = hv;
                if (y_out) {
                    float dd = dis[r]; float idg = dd*dd;
                    *(float4*)&y_out[(size_t)r*64 + tc] =
                        make_float4(acc[i][0]*idg+bc[0], acc[i][1]*idg+bc[1],
                                    acc[i][2]*idg+bc[2], acc[i][3]*idg+bc[3]);
                }
            }
        }
    } else {
        float ps[4] = {0,0,0,0}, pq[4] = {0,0,0,0};
        #pragma unroll
        for (int i = 0; i < 4; ++i) {
            int r = rowbase + tr + i;
            if (r < NN) {
                float y0 = acc[i][0]+bc[0], y1 = acc[i][1]+bc[1];
                float y2 = acc[i][2]+bc[2], y3 = acc[i][3]+bc[3];
                *(float4*)&y_out[(size_t)r*64 + tc] = make_float4(y0,y1,y2,y3);
                ps[0]+=y0; ps[1]+=y1; ps[2]+=y2; ps[3]+=y3;
                pq[0]+=y0*y0; pq[1]+=y1*y1; pq[2]+=y2*y2; pq[3]+=y3*y3;
            }
        }
        __syncthreads();
        int grp = tid >> 4;
        #pragma unroll
        for (int j = 0; j < 4; ++j) { xs[grp*64 + tc+j] = ps[j]; ws[grp*64 + tc+j] = pq[j]; }
        __syncthreads();
        if (tid < 64) {
            float s = 0.f, q = 0.f;
            #pragma unroll
            for (int g2 = 0; g2 < 16; ++g2) { s += xs[g2*64+tid]; q += ws[g2*64+tid]; }
            unsafeAtomicAdd(&outsums[tid], s);
            unsafeAtomicAdd(&outsums[64+tid], q);
        }
    }
}

__global__ __launch_bounds__(256) void k_final(
    const int* __restrict__ flag, const float* __restrict__ y3,
    const void* __restrict__ g, const void* __restrict__ bb,
    const float* __restrict__ sums, const void* __restrict__ w2,
    const void* __restrict__ b2, void* __restrict__ out) {
    __shared__ __align__(16) float tile[64*64];
    __shared__ float wp[64], tv[64];
    const int f = flag[0];
    const int tid = threadIdx.x;
    const int base = blockIdx.x * 64;
    if (tid < 64) {
        float mean = sums[tid] * INV_N;
        float var  = fmaxf(sums[64+tid] * INV_N - mean*mean, 0.f);
        float s = ld1(g, tid, f) * rsqrtf(var + BN_EPS);
        float t = ld1(bb, tid, f) - mean*s;
        float w = ld1(w2, tid, f);
        wp[tid] = s*w; tv[tid] = t*w;
    }
    #pragma unroll
    for (int it = 0; it < 4; ++it) {
        int i4 = it*256 + tid;
        int row = i4 >> 4;
        float4 v = make_float4(0,0,0,0);
        if (base + row < NN) v = *(const float4*)&y3[(size_t)base*64 + i4*4];
        *(float4*)&tile[i4*4] = v;
    }
    __syncthreads();
    if (tid < 64 && base + tid < NN) {
        float a = ld1(b2, 0, f);
        #pragma unroll
        for (int c = 0; c < 64; ++c) a += tv[c];
        #pragma unroll
        for (int cc = 0; cc < 64; ++cc) {
            int c = (cc + tid) & 63;
            a += tile[tid*64 + c] * wp[c];
        }
        if (f) ((float*)out)[base + tid] = a;
        else   ((unsigned short*)out)[base + tid] = f2bf(a);
    }
}

extern "C" void kernel_launch(void* const* d_in, const int* in_sizes, int n_in,
                              void* d_out, int out_size, void* d_ws, size_t ws_size,
                              hipStream_t stream) {
    const unsigned short* x = (const unsigned short*)d_in[0];
    const void* ew  = d_in[1];
    const void* W1  = d_in[2];
    const void* b1  = d_in[3];
    const void* W2  = d_in[4];
    const void* b2  = d_in[5];
    const void* l1W = d_in[6];
    const void* l1b = d_in[7];
    const void* l2W = d_in[8];
    const void* l2b = d_in[9];
    const void* g1  = d_in[10];
    const void* bb1 = d_in[11];
    const void* g2  = d_in[12];
    const void* bb2 = d_in[13];
    const void* g3  = d_in[14];
    const void* bb3 = d_in[15];
    const int* eidx = (const int*)d_in[16];

    // common layout (float idx): flag 0, sums 16, dis 400, agg 100400..6500400,
    // hbuf(ushort) 6500400..9700400
    int*   flag = (int*)d_ws;
    float* wsf  = (float*)d_ws;
    float* sums = wsf + 16;
    float* dis  = wsf + 400;
    float* agg  = wsf + 100400;
    unsigned short* hbuf = (unsigned short*)(wsf + 6500400);

    // fast-path overlay (== proven 66,011,328 B):
    // histmat/rowptr 9700400 (400,384 ints), btot 10100784, bstart 10101808,
    // edata(int2) 10102832. Unsorted scratch scr(int2) in agg region.
    int*  histmat = (int*)(wsf + 9700400);
    int*  rowptr2 = histmat;
    int*  btot    = (int*)(wsf + 10100784);
    int*  bstart  = (int*)(wsf + 10101808);
    int2* edata   = (int2*)(wsf + 10102832);
    int2* scr     = (int2*)(wsf + 100400);
    const size_t NEED_NEW = (size_t)16502832 * 4;

    // R3 fallback overlay
    int*   rowptr   = (int*)(wsf + 9700400);
    int*   cursor   = (int*)(wsf + 9800400);
    int*   blocksum = (int*)(wsf + 9900400);
    int*   srcs     = (int*)(wsf + 9900912);
    float* coefs    = wsf + 13100912;
    const size_t NEED_CSR = (size_t)16300912 * 4;

    if (ws_size < NEED_CSR) return;
    const bool fast = ws_size >= NEED_NEW;

    if (fast) {
        k_detect2  <<<1, 256, 0, stream>>>(x, eidx, flag, sums);
        k_hist     <<<NSB, 256, 0, stream>>>(flag, eidx, histmat);
        k_scanA    <<<NBK, 256, 0, stream>>>(histmat, btot);
        k_scanB    <<<1, 1024, 0, stream>>>(btot, bstart);
        k_scatter  <<<NSB, 256, 0, stream>>>(flag, eidx, ew, histmat, bstart, scr);
        k_sortdeg  <<<NBK, 256, 0, stream>>>(bstart, scr, edata, rowptr2, dis);
        // layer 1
        k_gemm1    <<<1563, 256, 0, stream>>>(flag, x, W1, b1, dis, hbuf, nullptr);
        k_gather3  <<<NN/4, 256, 0, stream>>>(flag, rowptr2, bstart, edata,
                                              dis, b1, hbuf, agg);
        k_bnstats4 <<<512, 256, 0, stream>>>((const float4*)agg, sums + 0, 1);
        // layer 2
        k_gemm64<true, true><<<1563, 256, 0, stream>>>(flag, agg, W2, b2, g1, bb1,
                                                       sums + 0, dis, hbuf, nullptr, nullptr);
        k_gather3  <<<NN/4, 256, 0, stream>>>(flag, rowptr2, bstart, edata,
                                              dis, b2, hbuf, agg);
    } else {
        k_detect2<<<1, 256, 0, stream>>>(x, eidx, flag, sums);
        k_init  <<<391, 256, 0, stream>>>(dis, sums, cursor);
        k_deg   <<<NE/256, 256, 0, stream>>>(flag, eidx, ew, dis, cursor);
        k_rsqrt <<<391, 256, 0, stream>>>(dis);
        k_scan1 <<<391, 256, 0, stream>>>(cursor, rowptr, blocksum);
        k_scan2 <<<1, 512, 0, stream>>>(blocksum);
        k_scan3 <<<391, 256, 0, stream>>>(rowptr, blocksum, cursor);
        k_fill  <<<NE/256, 256, 0, stream>>>(flag, eidx, ew, dis, cursor, srcs, coefs);
        k_gemm1 <<<1563, 256, 0, stream>>>(flag, x, W1, b1, dis, hbuf, nullptr);
        k_gather<<<NN/4, 256, 0, stream>>>(flag, rowptr, cursor, srcs, coefs,
                                           dis, b1, hbuf, agg);
        k_bnstats4<<<512, 256, 0, stream>>>((const float4*)agg, sums + 0, 1);
        k_gemm64<true, true><<<1563, 256, 0, stream>>>(flag, agg, W2, b2, g1, bb1,
                                                       sums + 0, dis, hbuf, nullptr, nullptr);
        k_gather<<<NN/4, 256, 0, stream>>>(flag, rowptr, cursor, srcs, coefs,
                                           dis, b2, hbuf, agg);
    }
    k_bnstats4<<<512, 256, 0, stream>>>((const float4*)agg, sums + 128, 0);
    k_gemm64<false, false><<<1563, 256, 0, stream>>>(flag, agg, l1W, l1b, g2, bb2,
                                                     sums + 128, dis, hbuf, agg, sums + 256);
    k_final <<<1563, 256, 0, stream>>>(flag, agg, g3, bb3, sums + 256, l2W, l2b, d_out);
}

// Round 8
// 612.341 us; speedup vs baseline: 5.2160x; 1.0323x over previous
//
#include <hip/hip_runtime.h>
#include <hip/hip_bf16.h>

// R8: (1) h stored pre-scaled by dis[row] (gemm epilogues) -> gather coef =
// w*dis[dst], no per-edge dis[src] load. (2) edata packed to 4B: src(17b) |
// w as 15-bit bf16 (RNE truncate; decode = single AND). (3) sortdeg on
// 64-node buckets with LDS out-staging -> coalesced edata writes (was ~205MB
// scattered-line RMW). ws need drops to 54.8 MB (proven >= 66 MB).

#define NN 100000
#define NE 3200000
#define INV_N (1.0f/100000.0f)
#define BN_EPS 1e-5f
#define NBK2 1563          // buckets of 64 nodes (fast path)
#define NSB 512            // scatter/hist blocks
#define EPB 6250           // edges per scatter/hist block (NSB*EPB == NE)
#define CAP2 4608          // LDS staging per bucket (mean 2046, 57 sigma)

static __device__ __forceinline__ float bf2f(unsigned short u) {
    if ((u & 0x7f80u) == 0x7f80u) u = 0;          // inf/NaN -> 0 (input scrub)
    union { unsigned int i; float f; } z; z.i = ((unsigned int)u) << 16; return z.f;
}
static __device__ __forceinline__ float scrubf(float v) {
    return (fabsf(v) < 1e30f) ? v : 0.f;
}
static __device__ __forceinline__ unsigned short f2bf(float v) {
    union { float f; unsigned int i; } z; z.f = v;
    unsigned int lsb = (z.i >> 16) & 1u; z.i += 0x7fffu + lsb;
    return (unsigned short)(z.i >> 16);
}
static __device__ __forceinline__ float ld1(const void* p, size_t i, int f) {
    return f ? scrubf(((const float*)p)[i]) : bf2f(((const unsigned short*)p)[i]);
}
static __device__ __forceinline__ float4 ld4(const void* p, size_t g, int f) {
    if (f) { float4 v = ((const float4*)p)[g];
             return make_float4(scrubf(v.x),scrubf(v.y),scrubf(v.z),scrubf(v.w)); }
    ushort4 u = ((const ushort4*)p)[g];
    return make_float4(bf2f(u.x),bf2f(u.y),bf2f(u.z),bf2f(u.w));
}
static __device__ __forceinline__ int getidx(const int* ei, size_t pos, int i64) {
    return i64 ? ei[2*pos] : ei[pos];
}
static __device__ __forceinline__ float blo(unsigned v) {
    union { unsigned u; float f; } z; z.u = v << 16; return z.f;
}
static __device__ __forceinline__ float bhi(unsigned v) {
    union { unsigned u; float f; } z; z.u = v & 0xffff0000u; return z.f;
}
static __device__ __forceinline__ unsigned packw15(unsigned s, unsigned wu) {
    unsigned lsb = (wu >> 17) & 1u;
    unsigned w15 = (wu + 0xFFFFu + lsb) >> 17;    // RNE to 1+8+6 bits
    return (s & 0x1ffffu) | (w15 << 17);
}

// ---------------- detector + sums zero ----------------
__global__ void k_detect2(const unsigned short* __restrict__ x,
                          const int* __restrict__ ei, int* __restrict__ flag,
                          float* __restrict__ sums) {
    __shared__ int cnt[256];
    int tid = threadIdx.x, c = 0;
    for (int i = tid; i < 1024; i += 256) {
        unsigned short u = x[i];
        int ex = (u >> 7) & 0xff;
        if ((u & 0x7fffu) != 0 && (ex >= 0xB0 || ex <= 0x40)) c++;
    }
    cnt[tid] = c; __syncthreads();
    if (tid == 0) { int t = 0; for (int i = 0; i < 256; ++i) t += cnt[i];
                    flag[0] = (t > 64) ? 1 : 0; }
    if (tid == 1) { int nz = 0; for (int i = 1; i < 64; i += 2) nz |= ei[i];
                    flag[1] = (nz == 0) ? 1 : 0; }
    if (tid < 128) { sums[tid]=0.f; sums[128+tid]=0.f; sums[256+tid]=0.f; }
}

// ================= bucket counting sort (no global atomics) =================

__global__ __launch_bounds__(256) void k_hist(const int* __restrict__ flag,
                                              const int* __restrict__ ei,
                                              int* __restrict__ histmat) {
    __shared__ int hh[NBK2];
    const int i64 = flag[1];
    const int blk = blockIdx.x, tid = threadIdx.x;
    for (int b = tid; b < NBK2; b += 256) hh[b] = 0;
    __syncthreads();
    const size_t e0 = (size_t)blk * EPB;
    for (int e = tid; e < EPB; e += 256) {
        unsigned d = (unsigned)getidx(ei, NE + e0 + e, i64);
        if (d < NN) atomicAdd(&hh[d >> 6], 1);
    }
    __syncthreads();
    for (int b = tid; b < NBK2; b += 256) histmat[blk*NBK2 + b] = hh[b];
}

__global__ __launch_bounds__(256) void k_scanA(int* __restrict__ histmat,
                                               int* __restrict__ btot) {
    __shared__ int sd[256];
    const int b = blockIdx.x, t = threadIdx.x;
    int v0 = histmat[(2*t)*NBK2 + b];
    int v1 = histmat[(2*t+1)*NBK2 + b];
    int ts = v0 + v1;
    sd[t] = ts; __syncthreads();
    #pragma unroll
    for (int ofs = 1; ofs < 256; ofs <<= 1) {
        int a = (t >= ofs) ? sd[t-ofs] : 0;
        __syncthreads(); sd[t] += a; __syncthreads();
    }
    int excl = sd[t] - ts;
    histmat[(2*t)*NBK2 + b]   = excl;
    histmat[(2*t+1)*NBK2 + b] = excl + v0;
    if (t == 255) btot[b] = sd[255];
}

__global__ void k_scanB(const int* __restrict__ btot, int* __restrict__ bstart) {
    __shared__ int sd[1024];
    int t = threadIdx.x;                 // 1024 threads, 2 elems each
    int i0 = 2*t, i1 = 2*t + 1;
    int v0 = (i0 < NBK2) ? btot[i0] : 0;
    int v1 = (i1 < NBK2) ? btot[i1] : 0;
    int ts = v0 + v1;
    sd[t] = ts; __syncthreads();
    #pragma unroll
    for (int ofs = 1; ofs < 1024; ofs <<= 1) {
        int a = (t >= ofs) ? sd[t-ofs] : 0;
        __syncthreads(); sd[t] += a; __syncthreads();
    }
    int excl = sd[t] - ts;
    if (i0 <= NBK2) bstart[i0] = excl;
    if (i1 <= NBK2) bstart[i1] = excl + v0;
}

// scatter edges -> scratch (bucket-grouped int2 {dloc<<17|src, w}); LDS atomics only
__global__ __launch_bounds__(256) void k_scatter(
    const int* __restrict__ flag, const int* __restrict__ ei,
    const void* __restrict__ ew, const int* __restrict__ histmat,
    const int* __restrict__ bstart, int2* __restrict__ scr) {
    __shared__ int cursor[NBK2];
    const int f = flag[0], i64 = flag[1];
    const int blk = blockIdx.x, tid = threadIdx.x;
    for (int b = tid; b < NBK2; b += 256)
        cursor[b] = histmat[blk*NBK2 + b] + bstart[b];
    __syncthreads();
    const size_t e0 = (size_t)blk * EPB;
    for (int e = tid; e < EPB; e += 256) {
        unsigned d = (unsigned)getidx(ei, NE + e0 + e, i64);
        if (d >= NN) continue;
        unsigned s = (unsigned)getidx(ei, e0 + e, i64);
        float w = ld1(ew, e0 + e, f);
        if (s >= NN) { s = 0; w = 0.f; }
        int pos = atomicAdd(&cursor[d >> 6], 1);
        scr[pos] = make_int2((int)(((d & 63u) << 17) | s), __float_as_int(w));
    }
}

// fused per-bucket node-sort + degree, coalesced edata write via LDS staging.
// edata = packed {w15<<17 | src}. Overflow (n > CAP2, never here): correct
// scattered-write path.
__global__ __launch_bounds__(256) void k_sortdeg(
    const int* __restrict__ bstart, const int2* __restrict__ scr,
    unsigned* __restrict__ edata, int* __restrict__ rowptr, float* __restrict__ dis) {
    __shared__ unsigned sp[CAP2];
    __shared__ unsigned out[CAP2];
    __shared__ int cnt[64], scn[64], cur[64];
    __shared__ float degf[64];
    const int b = blockIdx.x, tid = threadIdx.x;
    const int node0 = b * 64;
    const int r0 = bstart[b], r1 = bstart[b+1], n = r1 - r0;
    const bool fit = (n <= CAP2);

    if (tid < 64) { cnt[tid] = 0; degf[tid] = 1.0f; }
    __syncthreads();
    if (fit) {
        for (int j = tid; j < n; j += 256) {
            int2 m = scr[r0 + j];
            sp[j] = (unsigned)m.x;
            int l = (m.x >> 17) & 63;
            atomicAdd(&cnt[l], 1);
            atomicAdd(&degf[l], __int_as_float(m.y));
        }
    } else {
        for (int j = tid; j < n; j += 256) {
            int2 m = scr[r0 + j];
            int l = (m.x >> 17) & 63;
            atomicAdd(&cnt[l], 1);
            atomicAdd(&degf[l], __int_as_float(m.y));
        }
    }
    __syncthreads();
    if (tid < 64) scn[tid] = cnt[tid];
    __syncthreads();
    #pragma unroll
    for (int ofs = 1; ofs < 64; ofs <<= 1) {
        int a = 0;
        if (tid < 64 && tid >= ofs) a = scn[tid - ofs];
        __syncthreads();
        if (tid < 64) scn[tid] += a;
        __syncthreads();
    }
    if (tid < 64) {
        int excl = scn[tid] - cnt[tid];
        cur[tid] = excl;
        int node = node0 + tid;
        if (node <= NN) rowptr[node] = r0 + excl;
        if (node <  NN) dis[node] = rsqrtf(fmaxf(degf[tid], 1e-12f));
    }
    __syncthreads();
    if (fit) {
        for (int j = tid; j < n; j += 256) {
            unsigned p = sp[j];
            int l = (p >> 17) & 63;
            int pos = atomicAdd(&cur[l], 1);
            unsigned wu = (unsigned)scr[r0 + j].y;   // L2-warm coalesced re-read
            out[pos] = packw15(p, wu);
        }
        __syncthreads();
        for (int j = tid; j < n; j += 256)           // coalesced linear write
            edata[r0 + j] = out[j];
    } else {
        for (int j = tid; j < n; j += 256) {
            int2 m = scr[r0 + j];
            int l = (m.x >> 17) & 63;
            int pos = atomicAdd(&cur[l], 1);
            edata[r0 + pos] = packw15((unsigned)m.x, (unsigned)m.y);
        }
    }
}

// gather: wave per node; h pre-scaled by dis[src]; coef = w15 * dis[dst].
// 8 edges in flight per iteration (4 per half-wave); uint = 2 bf16 features.
__global__ __launch_bounds__(256) void k_gather3(
    const int* __restrict__ flag, const int* __restrict__ rowptr,
    const int* __restrict__ bstart, const unsigned* __restrict__ edata,
    const float* __restrict__ dis, const void* __restrict__ bias,
    const unsigned short* __restrict__ h, float* __restrict__ agg) {
    const int f = flag[0];
    const int node = blockIdx.x * 4 + (threadIdx.x >> 6);  // grid exact NN/4
    const int lane = threadIdx.x & 63;
    const int li = lane & 31, hi = lane >> 5;
    const float d2 = dis[node];
    const unsigned* h32 = (const unsigned*)h;
    float a0 = 0.f, a1 = 0.f;
    if (hi == 0) {
        unsigned hv = h32[(size_t)node*32 + li];      // h' = dis*h -> d2*h' = dis^2*h
        a0 = ld1(bias, 2*li,   f) + d2 * blo(hv);
        a1 = ld1(bias, 2*li+1, f) + d2 * bhi(hv);
    }
    int j = rowptr[node];
    const int end = ((node & 63) == 63) ? bstart[(node >> 6) + 1] : rowptr[node + 1];
    for (; j + 7 < end; j += 8) {
        unsigned m0 = edata[j +     hi];
        unsigned m1 = edata[j + 2 + hi];
        unsigned m2 = edata[j + 4 + hi];
        unsigned m3 = edata[j + 6 + hi];
        unsigned v0 = h32[(size_t)(m0 & 0x1ffffu)*32 + li];
        unsigned v1 = h32[(size_t)(m1 & 0x1ffffu)*32 + li];
        unsigned v2 = h32[(size_t)(m2 & 0x1ffffu)*32 + li];
        unsigned v3 = h32[(size_t)(m3 & 0x1ffffu)*32 + li];
        float c0 = __int_as_float((int)(m0 & 0xFFFE0000u)) * d2;
        float c1 = __int_as_float((int)(m1 & 0xFFFE0000u)) * d2;
        float c2 = __int_as_float((int)(m2 & 0xFFFE0000u)) * d2;
        float c3 = __int_as_float((int)(m3 & 0xFFFE0000u)) * d2;
        a0 = fmaf(c0, blo(v0), a0); a1 = fmaf(c0, bhi(v0), a1);
        a0 = fmaf(c1, blo(v1), a0); a1 = fmaf(c1, bhi(v1), a1);
        a0 = fmaf(c2, blo(v2), a0); a1 = fmaf(c2, bhi(v2), a1);
        a0 = fmaf(c3, blo(v3), a0); a1 = fmaf(c3, bhi(v3), a1);
    }
    for (; j + 1 < end; j += 2) {
        unsigned m0 = edata[j + hi];
        unsigned v0 = h32[(size_t)(m0 & 0x1ffffu)*32 + li];
        float c0 = __int_as_float((int)(m0 & 0xFFFE0000u)) * d2;
        a0 = fmaf(c0, blo(v0), a0); a1 = fmaf(c0, bhi(v0), a1);
    }
    if (j < end && hi == 0) {
        unsigned m0 = edata[j];
        unsigned v0 = h32[(size_t)(m0 & 0x1ffffu)*32 + li];
        float c0 = __int_as_float((int)(m0 & 0xFFFE0000u)) * d2;
        a0 = fmaf(c0, blo(v0), a0); a1 = fmaf(c0, bhi(v0), a1);
    }
    a0 += __shfl_xor(a0, 32);
    a1 += __shfl_xor(a1, 32);
    if (hi == 0)
        *(float2*)&agg[(size_t)node*64 + 2*li] = make_float2(a0, a1);
}

// ================= FALLBACK (R3) kernels =================

__global__ void k_init(float* __restrict__ dis, float* __restrict__ sums,
                       int* __restrict__ cnt) {
    int i = blockIdx.x * 256 + threadIdx.x;
    if (i < NN)  dis[i] = 1.0f;
    if (i < 384) sums[i] = 0.0f;
    if (cnt && i < NN) cnt[i] = 0;
}
__global__ void k_deg(const int* __restrict__ flag, const int* __restrict__ ei,
                      const void* __restrict__ ew, float* __restrict__ deg,
                      int* __restrict__ cnt) {
    const int f = flag[0], i64 = flag[1];
    int e = blockIdx.x * 256 + threadIdx.x;
    unsigned d = (unsigned)getidx(ei, NE + (size_t)e, i64);
    if (d < NN) {
        unsafeAtomicAdd(&deg[d], ld1(ew, e, f));
        if (cnt) atomicAdd(&cnt[d], 1);
    }
}
__global__ void k_rsqrt(float* __restrict__ dis) {
    int i = blockIdx.x * 256 + threadIdx.x;
    if (i < NN) dis[i] = rsqrtf(fmaxf(dis[i], 1e-12f));
}
__global__ void k_scan1(const int* __restrict__ cnt, int* __restrict__ rowptr,
                        int* __restrict__ blocksum) {
    __shared__ int sd[256];
    int t = threadIdx.x, i = blockIdx.x*256 + t;
    int v = (i < NN) ? cnt[i] : 0;
    sd[t] = v; __syncthreads();
    #pragma unroll
    for (int ofs = 1; ofs < 256; ofs <<= 1) {
        int a = (t >= ofs) ? sd[t-ofs] : 0;
        __syncthreads(); sd[t] += a; __syncthreads();
    }
    if (i < NN) rowptr[i] = sd[t] - v;
    if (t == 255) blocksum[blockIdx.x] = sd[255];
}
__global__ void k_scan2(int* __restrict__ blocksum) {
    __shared__ int sd[512];
    int t = threadIdx.x;
    int v = (t < 391) ? blocksum[t] : 0;
    sd[t] = v; __syncthreads();
    #pragma unroll
    for (int ofs = 1; ofs < 512; ofs <<= 1) {
        int a = (t >= ofs) ? sd[t-ofs] : 0;
        __syncthreads(); sd[t] += a; __syncthreads();
    }
    if (t < 391) blocksum[t] = sd[t] - v;
}
__global__ void k_scan3(int* __restrict__ rowptr, const int* __restrict__ blocksum,
                        int* __restrict__ cursor) {
    int i = blockIdx.x*256 + threadIdx.x;
    if (i < NN) { int r = rowptr[i] + blocksum[blockIdx.x]; rowptr[i] = r; cursor[i] = r; }
}
__global__ void k_fill(const int* __restrict__ flag, const int* __restrict__ ei,
                       const void* __restrict__ ew, const float* __restrict__ dis,
                       int* __restrict__ cursor, int* __restrict__ srcs,
                       float* __restrict__ coefs) {
    const int f = flag[0], i64 = flag[1];
    int e = blockIdx.x * 256 + threadIdx.x;
    unsigned s = (unsigned)getidx(ei, (size_t)e, i64);
    unsigned d = (unsigned)getidx(ei, NE + (size_t)e, i64);
    if (s >= NN || d >= NN) return;
    float coef = dis[s] * ld1(ew, e, f) * dis[d];
    int pos = atomicAdd(&cursor[d], 1);
    srcs[pos] = (int)s;
    coefs[pos] = coef;
}
__global__ __launch_bounds__(256) void k_gather(
    const int* __restrict__ flag, const int* __restrict__ rowptr,
    const int* __restrict__ rowend, const int* __restrict__ srcs,
    const float* __restrict__ coefs, const float* __restrict__ dis,
    const void* __restrict__ bias, const unsigned short* __restrict__ h,
    float* __restrict__ agg) {
    const int f = flag[0];
    int node = blockIdx.x * 4 + (threadIdx.x >> 6);
    int lane = threadIdx.x & 63;
    float d2 = dis[node];
    float acc = ld1(bias, lane, f) + d2*d2*bf2f(h[(size_t)node*64 + lane]);
    int j = rowptr[node], end = rowend[node];
    for (; j < end; ++j)
        acc = fmaf(coefs[j], bf2f(h[(size_t)srcs[j]*64 + lane]), acc);
    agg[(size_t)node*64 + lane] = acc;
}

// ================= dense kernels =================

__global__ __launch_bounds__(256) void k_gemm1(
    const int* __restrict__ flag, const void* __restrict__ x,
    const void* __restrict__ W, const void* __restrict__ bias,
    const float* __restrict__ dis, int presc,
    unsigned short* __restrict__ h_out, float* __restrict__ agg_out) {
    __shared__ __align__(16) float ws[128*64];
    __shared__ __align__(16) float xs[64*64];
    const int f = flag[0];
    const int tid = threadIdx.x;
    const int rowbase = blockIdx.x * 64;
    #pragma unroll
    for (int it = 0; it < 8; ++it) {
        int g = it*256 + tid;
        float4 v = ld4(W, g, f);
        int b = g*4;
        ws[b]=v.x; ws[b+1]=v.y; ws[b+2]=v.z; ws[b+3]=v.w;
    }
    const int tr = (tid >> 4) << 2;
    const int tc = (tid & 15) << 2;
    const int row = tid & 63;
    const int grow = rowbase + row;
    const bool valid = grow < NN;
    float acc[4][4] = {};
    for (int half = 0; half < 2; ++half) {
        __syncthreads();
        #pragma unroll
        for (int it = 0; it < 4; ++it) {
            int f4 = (tid >> 6) + it*4;
            int kl = f4*4;
            float4 v = make_float4(0,0,0,0);
            if (valid) v = ld4(x, (size_t)grow*32 + half*16 + f4, f);
            xs[(kl+0)*64+row]=v.x; xs[(kl+1)*64+row]=v.y;
            xs[(kl+2)*64+row]=v.z; xs[(kl+3)*64+row]=v.w;
        }
        __syncthreads();
        #pragma unroll 8
        for (int k = 0; k < 64; ++k) {
            const float4 av = *(const float4*)&xs[k*64 + tr];
            const float4 wv = *(const float4*)&ws[(half*64 + k)*64 + tc];
            const float aa[4] = {av.x, av.y, av.z, av.w};
            const float ww[4] = {wv.x, wv.y, wv.z, wv.w};
            #pragma unroll
            for (int i = 0; i < 4; ++i)
                #pragma unroll
                for (int j = 0; j < 4; ++j)
                    acc[i][j] = fmaf(aa[i], ww[j], acc[i][j]);
        }
    }
    float bc[4];
    #pragma unroll
    for (int j = 0; j < 4; ++j) bc[j] = ld1(bias, tc+j, f);
    #pragma unroll
    for (int i = 0; i < 4; ++i) {
        int r = rowbase + tr + i;
        if (r < NN) {
            float dd = dis[r];
            float hm = presc ? dd : 1.0f;
            ushort4 hv = make_ushort4(f2bf(acc[i][0]*hm), f2bf(acc[i][1]*hm),
                                      f2bf(acc[i][2]*hm), f2bf(acc[i][3]*hm));
            *(ushort4*)&h_out[(size_t)r*64 + tc] = hv;
            if (agg_out) {
                float idg = dd*dd;
                *(float4*)&agg_out[(size_t)r*64 + tc] =
                    make_float4(acc[i][0]*idg+bc[0], acc[i][1]*idg+bc[1],
                                acc[i][2]*idg+bc[2], acc[i][3]*idg+bc[3]);
            }
        }
    }
}

// float4 BN column stats (optionally after relu); 512 blocks
__global__ __launch_bounds__(256) void k_bnstats4(const float4* __restrict__ src,
                                                  float* __restrict__ sumout, int relu) {
    const int tid = threadIdx.x;
    float s0=0,s1=0,s2=0,s3=0, q0=0,q1=0,q2=0,q3=0;
    for (int g = blockIdx.x*256 + tid; g < NN*16; g += 512*256) {
        float4 v = src[g];
        if (relu) { v.x=fmaxf(v.x,0.f); v.y=fmaxf(v.y,0.f);
                    v.z=fmaxf(v.z,0.f); v.w=fmaxf(v.w,0.f); }
        s0+=v.x; q0+=v.x*v.x; s1+=v.y; q1+=v.y*v.y;
        s2+=v.z; q2+=v.z*v.z; s3+=v.w; q3+=v.w*v.w;
    }
    __shared__ float ls[1024], lq[1024];
    ls[tid*4+0]=s0; ls[tid*4+1]=s1; ls[tid*4+2]=s2; ls[tid*4+3]=s3;
    lq[tid*4+0]=q0; lq[tid*4+1]=q1; lq[tid*4+2]=q2; lq[tid*4+3]=q3;
    __syncthreads();
    if (tid < 64) {
        int grp = tid >> 2, k = tid & 3;
        float s = 0.f, q = 0.f;
        #pragma unroll
        for (int m = 0; m < 16; ++m) {
            int idx = (grp + 16*m)*4 + k;
            s += ls[idx]; q += lq[idx];
        }
        unsafeAtomicAdd(&sumout[tid], s);
        unsafeAtomicAdd(&sumout[64+tid], q);
    }
}

template<bool RELU, bool AGG>
__global__ __launch_bounds__(256) void k_gemm64(
    const int* __restrict__ flag, const float* __restrict__ in,
    const void* __restrict__ W, const void* __restrict__ bias,
    const void* __restrict__ g, const void* __restrict__ bb,
    const float* __restrict__ insums, const float* __restrict__ dis, int presc,
    unsigned short* __restrict__ h_out, float* __restrict__ y_out,
    float* __restrict__ outsums) {
    __shared__ __align__(16) float ws[64*64];
    __shared__ __align__(16) float xs[64*64];
    __shared__ float sc[64], sh[64];
    const int f = flag[0];
    const int tid = threadIdx.x;
    const int rowbase = blockIdx.x * 64;
    if (tid < 64) {
        float mean = insums[tid] * INV_N;
        float var  = fmaxf(insums[64+tid] * INV_N - mean*mean, 0.f);
        float s = ld1(g, tid, f) * rsqrtf(var + BN_EPS);
        sc[tid] = s;
        sh[tid] = ld1(bb, tid, f) - mean*s;
    }
    #pragma unroll
    for (int it = 0; it < 4; ++it) {
        int gi = it*256 + tid;
        float4 v = ld4(W, gi, f);
        int b = gi*4;
        ws[b]=v.x; ws[b+1]=v.y; ws[b+2]=v.z; ws[b+3]=v.w;
    }
    __syncthreads();
    {
        int row = tid & 63;
        int grow = rowbase + row;
        bool valid = grow < NN;
        #pragma unroll
        for (int it = 0; it < 4; ++it) {
            int f4 = (tid >> 6) + it*4;
            int k = f4*4;
            float4 v = make_float4(0,0,0,0);
            if (valid) v = *(const float4*)&in[(size_t)grow*64 + k];
            float a0=v.x, a1=v.y, a2=v.z, a3=v.w;
            if (RELU) { a0=fmaxf(a0,0.f); a1=fmaxf(a1,0.f); a2=fmaxf(a2,0.f); a3=fmaxf(a3,0.f); }
            a0 = a0*sc[k+0]+sh[k+0]; a1 = a1*sc[k+1]+sh[k+1];
            a2 = a2*sc[k+2]+sh[k+2]; a3 = a3*sc[k+3]+sh[k+3];
            xs[(k+0)*64+row]=a0; xs[(k+1)*64+row]=a1;
            xs[(k+2)*64+row]=a2; xs[(k+3)*64+row]=a3;
        }
    }
    __syncthreads();
    const int tr = (tid >> 4) << 2;
    const int tc = (tid & 15) << 2;
    float acc[4][4] = {};
    #pragma unroll 8
    for (int k = 0; k < 64; ++k) {
        const float4 av = *(const float4*)&xs[k*64 + tr];
        const float4 wv = *(const float4*)&ws[k*64 + tc];
        const float aa[4] = {av.x, av.y, av.z, av.w};
        const float ww[4] = {wv.x, wv.y, wv.z, wv.w};
        #pragma unroll
        for (int i = 0; i < 4; ++i)
            #pragma unroll
            for (int j = 0; j < 4; ++j)
                acc[i][j] = fmaf(aa[i], ww[j], acc[i][j]);
    }
    float bc[4];
    #pragma unroll
    for (int j = 0; j < 4; ++j) bc[j] = ld1(bias, tc+j, f);
    if (AGG) {
        #pragma unroll
        for (int i = 0; i < 4; ++i) {
            int r = rowbase + tr + i;
            if (r < NN) {
                float dd = dis[r];
                float hm = presc ? dd : 1.0f;
                ushort4 hv = make_ushort4(f2bf(acc[i][0]*hm), f2bf(acc[i][1]*hm),
                                          f2bf(acc[i][2]*hm), f2bf(acc[i][3]*hm));
                *(ushort4*)&h_out[(size_t)r*64 + tc] = hv;
                if (y_out) {
                    float idg = dd*dd;
                    *(float4*)&y_out[(size_t)r*64 + tc] =
                        make_float4(acc[i][0]*idg+bc[0], acc[i][1]*idg+bc[1],
                                    acc[i][2]*idg+bc[2], acc[i][3]*idg+bc[3]);
                }
            }
        }
    } else {
        float ps[4] = {0,0,0,0}, pq[4] = {0,0,0,0};
        #pragma unroll
        for (int i = 0; i < 4; ++i) {
            int r = rowbase + tr + i;
            if (r < NN) {
                float y0 = acc[i][0]+bc[0], y1 = acc[i][1]+bc[1];
                float y2 = acc[i][2]+bc[2], y3 = acc[i][3]+bc[3];
                *(float4*)&y_out[(size_t)r*64 + tc] = make_float4(y0,y1,y2,y3);
                ps[0]+=y0; ps[1]+=y1; ps[2]+=y2; ps[3]+=y3;
                pq[0]+=y0*y0; pq[1]+=y1*y1; pq[2]+=y2*y2; pq[3]+=y3*y3;
            }
        }
        __syncthreads();
        int grp = tid >> 4;
        #pragma unroll
        for (int j = 0; j < 4; ++j) { xs[grp*64 + tc+j] = ps[j]; ws[grp*64 + tc+j] = pq[j]; }
        __syncthreads();
        if (tid < 64) {
            float s = 0.f, q = 0.f;
            #pragma unroll
            for (int g2 = 0; g2 < 16; ++g2) { s += xs[g2*64+tid]; q += ws[g2*64+tid]; }
            unsafeAtomicAdd(&outsums[tid], s);
            unsafeAtomicAdd(&outsums[64+tid], q);
        }
    }
}

__global__ __launch_bounds__(256) void k_final(
    const int* __restrict__ flag, const float* __restrict__ y3,
    const void* __restrict__ g, const void* __restrict__ bb,
    const float* __restrict__ sums, const void* __restrict__ w2,
    const void* __restrict__ b2, void* __restrict__ out) {
    __shared__ __align__(16) float tile[64*64];
    __shared__ float wp[64], tv[64];
    const int f = flag[0];
    const int tid = threadIdx.x;
    const int base = blockIdx.x * 64;
    if (tid < 64) {
        float mean = sums[tid] * INV_N;
        float var  = fmaxf(sums[64+tid] * INV_N - mean*mean, 0.f);
        float s = ld1(g, tid, f) * rsqrtf(var + BN_EPS);
        float t = ld1(bb, tid, f) - mean*s;
        float w = ld1(w2, tid, f);
        wp[tid] = s*w; tv[tid] = t*w;
    }
    #pragma unroll
    for (int it = 0; it < 4; ++it) {
        int i4 = it*256 + tid;
        int row = i4 >> 4;
        float4 v = make_float4(0,0,0,0);
        if (base + row < NN) v = *(const float4*)&y3[(size_t)base*64 + i4*4];
        *(float4*)&tile[i4*4] = v;
    }
    __syncthreads();
    if (tid < 64 && base + tid < NN) {
        float a = ld1(b2, 0, f);
        #pragma unroll
        for (int c = 0; c < 64; ++c) a += tv[c];
        #pragma unroll
        for (int cc = 0; cc < 64; ++cc) {
            int c = (cc + tid) & 63;
            a += tile[tid*64 + c] * wp[c];
        }
        if (f) ((float*)out)[base + tid] = a;
        else   ((unsigned short*)out)[base + tid] = f2bf(a);
    }
}

extern "C" void kernel_launch(void* const* d_in, const int* in_sizes, int n_in,
                              void* d_out, int out_size, void* d_ws, size_t ws_size,
                              hipStream_t stream) {
    const unsigned short* x = (const unsigned short*)d_in[0];
    const void* ew  = d_in[1];
    const void* W1  = d_in[2];
    const void* b1  = d_in[3];
    const void* W2  = d_in[4];
    const void* b2  = d_in[5];
    const void* l1W = d_in[6];
    const void* l1b = d_in[7];
    const void* l2W = d_in[8];
    const void* l2b = d_in[9];
    const void* g1  = d_in[10];
    const void* bb1 = d_in[11];
    const void* g2  = d_in[12];
    const void* bb2 = d_in[13];
    const void* g3  = d_in[14];
    const void* bb3 = d_in[15];
    const int* eidx = (const int*)d_in[16];

    // common layout (float idx): flag 0, sums 16, dis 400, agg 100400..6500400,
    // hbuf(ushort) 6500400..9700400
    int*   flag = (int*)d_ws;
    float* wsf  = (float*)d_ws;
    float* sums = wsf + 16;
    float* dis  = wsf + 400;
    float* agg  = wsf + 100400;
    unsigned short* hbuf = (unsigned short*)(wsf + 6500400);

    // fast-path overlay (54.8 MB, well under proven 66 MB):
    // histmat 9700400 (512*1563 = 800,256 ints; rowptr overlays after scatter),
    // btot 10500656 (1563), bstart 10502224 (1564), edata(uint) 10503792 (3.2M)
    int*      histmat = (int*)(wsf + 9700400);
    int*      rowptr2 = histmat;
    int*      btot    = (int*)(wsf + 10500656);
    int*      bstart  = (int*)(wsf + 10502224);
    unsigned* edata   = (unsigned*)(wsf + 10503792);
    int2*     scr     = (int2*)(wsf + 100400);       // in agg region
    const size_t NEED_NEW = (size_t)13703792 * 4;    // 54.8 MB

    // R3 fallback overlay
    int*   rowptr   = (int*)(wsf + 9700400);
    int*   cursor   = (int*)(wsf + 9800400);
    int*   blocksum = (int*)(wsf + 9900400);
    int*   srcs     = (int*)(wsf + 9900912);
    float* coefs    = wsf + 13100912;
    const size_t NEED_CSR = (size_t)16300912 * 4;

    if (ws_size < NEED_NEW) return;
    const bool fast = true;

    if (fast) {
        k_detect2  <<<1, 256, 0, stream>>>(x, eidx, flag, sums);
        k_hist     <<<NSB, 256, 0, stream>>>(flag, eidx, histmat);
        k_scanA    <<<NBK2, 256, 0, stream>>>(histmat, btot);
        k_scanB    <<<1, 1024, 0, stream>>>(btot, bstart);
        k_scatter  <<<NSB, 256, 0, stream>>>(flag, eidx, ew, histmat, bstart, scr);
        k_sortdeg  <<<NBK2, 256, 0, stream>>>(bstart, scr, edata, rowptr2, dis);
        // layer 1
        k_gemm1    <<<1563, 256, 0, stream>>>(flag, x, W1, b1, dis, 1, hbuf, nullptr);
        k_gather3  <<<NN/4, 256, 0, stream>>>(flag, rowptr2, bstart, edata,
                                              dis, b1, hbuf, agg);
        k_bnstats4 <<<512, 256, 0, stream>>>((const float4*)agg, sums + 0, 1);
        // layer 2
        k_gemm64<true, true><<<1563, 256, 0, stream>>>(flag, agg, W2, b2, g1, bb1,
                                                       sums + 0, dis, 1, hbuf, nullptr, nullptr);
        k_gather3  <<<NN/4, 256, 0, stream>>>(flag, rowptr2, bstart, edata,
                                              dis, b2, hbuf, agg);
    } else {
        // retained for reference; not reachable (NEED_NEW < NEED_CSR)
        k_detect2<<<1, 256, 0, stream>>>(x, eidx, flag, sums);
        k_init  <<<391, 256, 0, stream>>>(dis, sums, cursor);
        k_deg   <<<NE/256, 256, 0, stream>>>(flag, eidx, ew, dis, cursor);
        k_rsqrt <<<391, 256, 0, stream>>>(dis);
        k_scan1 <<<391, 256, 0, stream>>>(cursor, rowptr, blocksum);
        k_scan2 <<<1, 512, 0, stream>>>(blocksum);
        k_scan3 <<<391, 256, 0, stream>>>(rowptr, blocksum, cursor);
        k_fill  <<<NE/256, 256, 0, stream>>>(flag, eidx, ew, dis, cursor, srcs, coefs);
        k_gemm1 <<<1563, 256, 0, stream>>>(flag, x, W1, b1, dis, 0, hbuf, nullptr);
        k_gather<<<NN/4, 256, 0, stream>>>(flag, rowptr, cursor, srcs, coefs,
                                           dis, b1, hbuf, agg);
        k_bnstats4<<<512, 256, 0, stream>>>((const float4*)agg, sums + 0, 1);
        k_gemm64<true, true><<<1563, 256, 0, stream>>>(flag, agg, W2, b2, g1, bb1,
                                                       sums + 0, dis, 0, hbuf, nullptr, nullptr);
        k_gather<<<NN/4, 256, 0, stream>>>(flag, rowptr, cursor, srcs, coefs,
                                           dis, b2, hbuf, agg);
    }
    k_bnstats4<<<512, 256, 0, stream>>>((const float4*)agg, sums + 128, 0);
    k_gemm64<false, false><<<1563, 256, 0, stream>>>(flag, agg, l1W, l1b, g2, bb2,
                                                     sums + 128, dis, 1, hbuf, agg, sums + 256);
    k_final <<<1563, 256, 0, stream>>>(flag, agg, g3, bb3, sums + 256, l2W, l2b, d_out);
}